// Round 1
// baseline (558.494 us; speedup 1.0000x reference)
//
#include <hip/hip_runtime.h>
#include <math.h>

#define N_SEQ 2048
#define DM    512
#define NTOK  4096      // BATCH * N_SEQ
#define NH    8
#define HD    64
#define ATT_SCALE 0.125f  // 1/sqrt(64)

// ---------------- LayerNorm (input) ----------------
__global__ __launch_bounds__(128) void k_ln(const float* __restrict__ x,
                                            const float* __restrict__ g,
                                            const float* __restrict__ b,
                                            float* __restrict__ y) {
    int tk = blockIdx.x, t = threadIdx.x;
    float4 xv = ((const float4*)(x + (size_t)tk * DM))[t];
    float s = xv.x + xv.y + xv.z + xv.w;
    float q = xv.x*xv.x + xv.y*xv.y + xv.z*xv.z + xv.w*xv.w;
    for (int o = 32; o; o >>= 1) { s += __shfl_down(s, o); q += __shfl_down(q, o); }
    __shared__ float ls[2], lq[2];
    if ((t & 63) == 0) { ls[t >> 6] = s; lq[t >> 6] = q; }
    __syncthreads();
    s = ls[0] + ls[1]; q = lq[0] + lq[1];
    float mu = s * (1.f / DM);
    float var = q * (1.f / DM) - mu * mu;
    float rs = rsqrtf(var + 1e-5f);
    float4 gv = ((const float4*)g)[t], bv = ((const float4*)b)[t];
    float4 o;
    o.x = (xv.x - mu) * rs * gv.x + bv.x;
    o.y = (xv.y - mu) * rs * gv.y + bv.y;
    o.z = (xv.z - mu) * rs * gv.z + bv.z;
    o.w = (xv.w - mu) * rs * gv.w + bv.w;
    ((float4*)(y + (size_t)tk * DM))[t] = o;
}

// ---------------- fused Q/K/V/T1 GEMM: y = xn @ W.T ----------------
// blockIdx.z: 0=Q,1=K,2=V (store [b][h][n][d]), 3=T_w1 (tanh(+b1), row-major)
__global__ __launch_bounds__(256) void k_gemm_qkvt(
    const float* __restrict__ xn,
    const float* __restrict__ Wq, const float* __restrict__ Wk,
    const float* __restrict__ Wv, const float* __restrict__ Tw1,
    const float* __restrict__ Tb1,
    float* __restrict__ qb, float* __restrict__ kb, float* __restrict__ vb,
    float* __restrict__ th) {
    __shared__ float As[16][68], Ws[16][68];
    int t = threadIdx.x;
    int o0 = blockIdx.x * 64, m0 = blockIdx.y * 64, z = blockIdx.z;
    const float* W = (z == 0) ? Wq : (z == 1) ? Wk : (z == 2) ? Wv : Tw1;
    int lr = t >> 2, lc = (t & 3) << 2;
    int tx = t & 15, ty = t >> 4;
    float acc[4][4] = {};
    const float* Arow = xn + (size_t)(m0 + lr) * DM + lc;
    const float* Wrow = W + (size_t)(o0 + lr) * DM + lc;
    for (int k0 = 0; k0 < DM; k0 += 16) {
        float4 av = *(const float4*)(Arow + k0);
        float4 wv = *(const float4*)(Wrow + k0);
        __syncthreads();
        As[lc + 0][lr] = av.x; As[lc + 1][lr] = av.y; As[lc + 2][lr] = av.z; As[lc + 3][lr] = av.w;
        Ws[lc + 0][lr] = wv.x; Ws[lc + 1][lr] = wv.y; Ws[lc + 2][lr] = wv.z; Ws[lc + 3][lr] = wv.w;
        __syncthreads();
        #pragma unroll
        for (int kk = 0; kk < 16; kk++) {
            float4 a = *(const float4*)&As[kk][ty << 2];
            float4 b = *(const float4*)&Ws[kk][tx << 2];
            float aa[4] = {a.x, a.y, a.z, a.w}, bb[4] = {b.x, b.y, b.z, b.w};
            #pragma unroll
            for (int i = 0; i < 4; i++)
                #pragma unroll
                for (int j = 0; j < 4; j++) acc[i][j] += aa[i] * bb[j];
        }
    }
    if (z < 3) {
        float* dst = (z == 0) ? qb : (z == 1) ? kb : vb;
        int h = blockIdx.x;  // 64-col tile == one head
        #pragma unroll
        for (int i = 0; i < 4; i++) {
            int tk = m0 + (ty << 2) + i;
            int bi = tk >> 11, n = tk & (N_SEQ - 1);
            float4 o = {acc[i][0], acc[i][1], acc[i][2], acc[i][3]};
            *(float4*)(dst + (((size_t)bi * NH + h) * N_SEQ + n) * HD + (tx << 2)) = o;
        }
    } else {
        int c = o0 + (tx << 2);
        float4 bv = *(const float4*)(Tb1 + c);
        #pragma unroll
        for (int i = 0; i < 4; i++) {
            int tk = m0 + (ty << 2) + i;
            float4 o;
            o.x = tanhf(acc[i][0] + bv.x);
            o.y = tanhf(acc[i][1] + bv.y);
            o.z = tanhf(acc[i][2] + bv.z);
            o.w = tanhf(acc[i][3] + bv.w);
            *(float4*)(th + (size_t)tk * DM + c) = o;
        }
    }
}

// ---------------- proj GEMM: out = A @ Wo.T (plain) ----------------
__global__ __launch_bounds__(256) void k_gemm_proj(
    const float* __restrict__ A, const float* __restrict__ Wo,
    float* __restrict__ out) {
    __shared__ float As[16][68], Ws[16][68];
    int t = threadIdx.x;
    int o0 = blockIdx.x * 64, m0 = blockIdx.y * 64;
    int lr = t >> 2, lc = (t & 3) << 2;
    int tx = t & 15, ty = t >> 4;
    float acc[4][4] = {};
    const float* Arow = A + (size_t)(m0 + lr) * DM + lc;
    const float* Wrow = Wo + (size_t)(o0 + lr) * DM + lc;
    for (int k0 = 0; k0 < DM; k0 += 16) {
        float4 av = *(const float4*)(Arow + k0);
        float4 wv = *(const float4*)(Wrow + k0);
        __syncthreads();
        As[lc + 0][lr] = av.x; As[lc + 1][lr] = av.y; As[lc + 2][lr] = av.z; As[lc + 3][lr] = av.w;
        Ws[lc + 0][lr] = wv.x; Ws[lc + 1][lr] = wv.y; Ws[lc + 2][lr] = wv.z; Ws[lc + 3][lr] = wv.w;
        __syncthreads();
        #pragma unroll
        for (int kk = 0; kk < 16; kk++) {
            float4 a = *(const float4*)&As[kk][ty << 2];
            float4 b = *(const float4*)&Ws[kk][tx << 2];
            float aa[4] = {a.x, a.y, a.z, a.w}, bb[4] = {b.x, b.y, b.z, b.w};
            #pragma unroll
            for (int i = 0; i < 4; i++)
                #pragma unroll
                for (int j = 0; j < 4; j++) acc[i][j] += aa[i] * bb[j];
        }
    }
    #pragma unroll
    for (int i = 0; i < 4; i++) {
        int tk = m0 + (ty << 2) + i;
        float4 o = {acc[i][0], acc[i][1], acc[i][2], acc[i][3]};
        *(float4*)(out + (size_t)tk * DM + o0 + (tx << 2)) = o;
    }
}

// ---------------- T logits: th @ T_w2.T + b2 ----------------
__global__ __launch_bounds__(64) void k_tlogit(const float* __restrict__ th,
                                               const float* __restrict__ w2,
                                               const float* __restrict__ b2,
                                               float* __restrict__ lg) {
    int tk = blockIdx.x, t = threadIdx.x;
    const float* row = th + (size_t)tk * DM;
    float s = 0.f;
    #pragma unroll
    for (int j = 0; j < 8; j++) s += row[t + 64 * j] * w2[t + 64 * j];
    for (int o = 32; o; o >>= 1) s += __shfl_down(s, o);
    if (t == 0) lg[tk] = s + b2[0];
}

// ---------------- gate = softmax over sequence dim per batch ----------------
__global__ __launch_bounds__(1024) void k_gate(const float* __restrict__ lg,
                                               float* __restrict__ gate) {
    int b = blockIdx.x, t = threadIdx.x;
    __shared__ float red[16];
    float v0 = lg[b * N_SEQ + t], v1 = lg[b * N_SEQ + 1024 + t];
    float m = fmaxf(v0, v1);
    for (int o = 32; o; o >>= 1) m = fmaxf(m, __shfl_down(m, o));
    if ((t & 63) == 0) red[t >> 6] = m;
    __syncthreads();
    if (t < 64) {
        float x = (t < 16) ? red[t] : -INFINITY;
        for (int o = 8; o; o >>= 1) x = fmaxf(x, __shfl_down(x, o));
        if (t == 0) red[0] = x;
    }
    __syncthreads();
    float M = red[0];
    float e0 = __expf(v0 - M), e1 = __expf(v1 - M);
    float s = e0 + e1;
    __syncthreads();
    for (int o = 32; o; o >>= 1) s += __shfl_down(s, o);
    if ((t & 63) == 0) red[t >> 6] = s;
    __syncthreads();
    if (t < 64) {
        float x = (t < 16) ? red[t] : 0.f;
        for (int o = 8; o; o >>= 1) x += __shfl_down(x, o);
        if (t == 0) red[0] = x;
    }
    __syncthreads();
    float inv = 1.f / red[0];
    gate[b * N_SEQ + t] = e0 * inv;
    gate[b * N_SEQ + 1024 + t] = e1 * inv;
}

// ---------------- masked flash attention (fp32) ----------------
// grid (32 qtiles, 8 heads, 2 batch), block 256. LDS ~70KB -> 2 blocks/CU.
__global__ __launch_bounds__(256) void k_attn(const float* __restrict__ qb,
                                              const float* __restrict__ kb,
                                              const float* __restrict__ vb,
                                              float* __restrict__ ob) {
    __shared__ float Qt[HD][68];  // [d][row]   (transposed)
    __shared__ float Kt[HD][68];  // [d][col]   (transposed)
    __shared__ float Vs[64][68];  // [key][d]
    __shared__ float Pt[64][68];  // [col][row] (transposed P)
    int t = threadIdx.x;
    int qt = blockIdx.x, h = blockIdx.y, bi = blockIdx.z;
    int q0 = qt * 64;
    // head spec: 0,1 global; 2,3,4 window 64/128/256; 5,6,7 dilated w=64 dil=2/4/8
    int kind = (h < 2) ? 0 : (h < 5) ? 1 : 2;
    int w = (h == 2 || h >= 5) ? 64 : (h == 3) ? 128 : (h == 4) ? 256 : 0;
    int dsh = (h == 5) ? 1 : (h == 6) ? 2 : (h == 7) ? 3 : 0;
    int wmax = (kind == 0) ? (1 << 29) : (w << dsh);
    const size_t base = ((size_t)bi * NH + h) * N_SEQ * HD;
    const float* Q = qb + base;
    const float* K = kb + base;
    const float* V = vb + base;
    {   // stage Q transposed, pre-scaled
        int r = t >> 2, d0 = (t & 3) << 4;
        const float* qrow = Q + (size_t)(q0 + r) * HD + d0;
        #pragma unroll
        for (int p = 0; p < 4; p++) {
            float4 v = *(const float4*)(qrow + p * 4);
            Qt[d0 + p * 4 + 0][r] = v.x * ATT_SCALE;
            Qt[d0 + p * 4 + 1][r] = v.y * ATT_SCALE;
            Qt[d0 + p * 4 + 2][r] = v.z * ATT_SCALE;
            Qt[d0 + p * 4 + 3][r] = v.w * ATT_SCALE;
        }
    }
    int tx = t & 15, ty = t >> 4;
    float m_i[4], l_i[4], acc[4][4] = {};
    #pragma unroll
    for (int i = 0; i < 4; i++) { m_i[i] = -INFINITY; l_i[i] = 0.f; }
    int kmin = q0 - wmax; if (kmin < 0) kmin = 0;
    int kmax = q0 + 63 + wmax; if (kmax > N_SEQ - 1) kmax = N_SEQ - 1;
    for (int kt = kmin >> 6; kt <= (kmax >> 6); kt++) {
        int k0 = kt << 6;
        int r = t >> 2, d0 = (t & 3) << 4;
        const float* krow = K + (size_t)(k0 + r) * HD + d0;
        const float* vrow = V + (size_t)(k0 + r) * HD + d0;
        float4 kv[4], vv[4];
        #pragma unroll
        for (int p = 0; p < 4; p++) { kv[p] = *(const float4*)(krow + p * 4); vv[p] = *(const float4*)(vrow + p * 4); }
        __syncthreads();  // prior iteration's reads of Kt/Vs/Pt done
        #pragma unroll
        for (int p = 0; p < 4; p++) {
            Kt[d0 + p * 4 + 0][r] = kv[p].x;
            Kt[d0 + p * 4 + 1][r] = kv[p].y;
            Kt[d0 + p * 4 + 2][r] = kv[p].z;
            Kt[d0 + p * 4 + 3][r] = kv[p].w;
            *(float4*)&Vs[r][d0 + p * 4] = vv[p];
        }
        __syncthreads();
        // scores S[r][c] = sum_d Q[r][d]*K[c][d] (Q pre-scaled)
        float S[4][4] = {};
        #pragma unroll 8
        for (int d = 0; d < HD; d++) {
            float4 a = *(const float4*)&Qt[d][ty << 2];
            float4 b = *(const float4*)&Kt[d][tx << 2];
            float aa[4] = {a.x, a.y, a.z, a.w}, bb[4] = {b.x, b.y, b.z, b.w};
            #pragma unroll
            for (int i = 0; i < 4; i++)
                #pragma unroll
                for (int j = 0; j < 4; j++) S[i][j] += aa[i] * bb[j];
        }
        // mask
        #pragma unroll
        for (int i = 0; i < 4; i++) {
            int qi = q0 + (ty << 2) + i;
            #pragma unroll
            for (int j = 0; j < 4; j++) {
                int kj = k0 + (tx << 2) + j;
                int dlt = qi - kj; if (dlt < 0) dlt = -dlt;
                bool valid;
                if (kind == 0) valid = true;
                else if (kind == 1) valid = (dlt <= w);
                else valid = ((dlt & ((1 << dsh) - 1)) == 0) && ((dlt >> dsh) <= w);
                if (!valid) S[i][j] = -INFINITY;
            }
        }
        // online softmax (rows spread over 16 consecutive lanes)
        #pragma unroll
        for (int i = 0; i < 4; i++) {
            float rm = fmaxf(fmaxf(S[i][0], S[i][1]), fmaxf(S[i][2], S[i][3]));
            rm = fmaxf(rm, __shfl_xor(rm, 1));
            rm = fmaxf(rm, __shfl_xor(rm, 2));
            rm = fmaxf(rm, __shfl_xor(rm, 4));
            rm = fmaxf(rm, __shfl_xor(rm, 8));
            float mn = fmaxf(m_i[i], rm);
            float sc = (mn == m_i[i]) ? 1.f : __expf(m_i[i] - mn);
            float rs_ = 0.f;
            #pragma unroll
            for (int j = 0; j < 4; j++) {
                float p = (S[i][j] == -INFINITY) ? 0.f : __expf(S[i][j] - mn);
                S[i][j] = p; rs_ += p;
            }
            rs_ += __shfl_xor(rs_, 1);
            rs_ += __shfl_xor(rs_, 2);
            rs_ += __shfl_xor(rs_, 4);
            rs_ += __shfl_xor(rs_, 8);
            l_i[i] = l_i[i] * sc + rs_;
            m_i[i] = mn;
            #pragma unroll
            for (int j = 0; j < 4; j++) acc[i][j] *= sc;
            #pragma unroll
            for (int j = 0; j < 4; j++) Pt[(tx << 2) + j][(ty << 2) + i] = S[i][j];
        }
        __syncthreads();  // Pt complete
        // acc += P @ V
        #pragma unroll 8
        for (int k = 0; k < 64; k++) {
            float4 a = *(const float4*)&Pt[k][ty << 2];
            float4 b = *(const float4*)&Vs[k][tx << 2];
            float aa[4] = {a.x, a.y, a.z, a.w}, bb[4] = {b.x, b.y, b.z, b.w};
            #pragma unroll
            for (int i = 0; i < 4; i++)
                #pragma unroll
                for (int j = 0; j < 4; j++) acc[i][j] += aa[i] * bb[j];
        }
    }
    // epilogue: write [b][n][h*64+d]
    #pragma unroll
    for (int i = 0; i < 4; i++) {
        float inv = 1.f / l_i[i];
        int n = q0 + (ty << 2) + i;
        float4 o = {acc[i][0] * inv, acc[i][1] * inv, acc[i][2] * inv, acc[i][3] * inv};
        *(float4*)(ob + (((size_t)bi * N_SEQ + n) * NH + h) * HD + (tx << 2)) = o;
    }
}

// ---------------- final: y = proj*gate + x0 ; LN_out ----------------
__global__ __launch_bounds__(128) void k_final(const float* __restrict__ proj,
                                               const float* __restrict__ gate,
                                               const float* __restrict__ x0,
                                               const float* __restrict__ g,
                                               const float* __restrict__ b,
                                               float* __restrict__ out) {
    int tk = blockIdx.x, t = threadIdx.x;
    float gt = gate[tk];
    float4 pv = ((const float4*)(proj + (size_t)tk * DM))[t];
    float4 xv = ((const float4*)(x0 + (size_t)tk * DM))[t];
    float4 y;
    y.x = pv.x * gt + xv.x;
    y.y = pv.y * gt + xv.y;
    y.z = pv.z * gt + xv.z;
    y.w = pv.w * gt + xv.w;
    float s = y.x + y.y + y.z + y.w;
    float q = y.x*y.x + y.y*y.y + y.z*y.z + y.w*y.w;
    for (int o = 32; o; o >>= 1) { s += __shfl_down(s, o); q += __shfl_down(q, o); }
    __shared__ float ls[2], lq[2];
    if ((t & 63) == 0) { ls[t >> 6] = s; lq[t >> 6] = q; }
    __syncthreads();
    s = ls[0] + ls[1]; q = lq[0] + lq[1];
    float mu = s * (1.f / DM);
    float var = q * (1.f / DM) - mu * mu;
    float rs = rsqrtf(var + 1e-5f);
    float4 gv = ((const float4*)g)[t], bv = ((const float4*)b)[t];
    float4 o;
    o.x = (y.x - mu) * rs * gv.x + bv.x;
    o.y = (y.y - mu) * rs * gv.y + bv.y;
    o.z = (y.z - mu) * rs * gv.z + bv.z;
    o.w = (y.w - mu) * rs * gv.w + bv.w;
    ((float4*)(out + (size_t)tk * DM))[t] = o;
}

extern "C" void kernel_launch(void* const* d_in, const int* in_sizes, int n_in,
                              void* d_out, int out_size, void* d_ws, size_t ws_size,
                              hipStream_t stream) {
    (void)in_sizes; (void)n_in; (void)out_size; (void)ws_size;
    const float* x    = (const float*)d_in[0];
    const float* Wq   = (const float*)d_in[1];
    const float* Wk   = (const float*)d_in[2];
    const float* Wv   = (const float*)d_in[3];
    const float* Wo   = (const float*)d_in[4];
    const float* Tw1  = (const float*)d_in[5];
    const float* Tb1  = (const float*)d_in[6];
    const float* Tw2  = (const float*)d_in[7];
    const float* Tb2  = (const float*)d_in[8];
    const float* ling = (const float*)d_in[9];
    const float* linb = (const float*)d_in[10];
    const float* logg = (const float*)d_in[11];
    const float* logb = (const float*)d_in[12];
    float* out = (float*)d_out;

    const size_t SZ = (size_t)NTOK * DM;  // 2,097,152 floats
    float* ws   = (float*)d_ws;
    float* xn   = ws;            // [4096,512]
    float* qb   = xn + SZ;       // [b][h][n][d]
    float* kb   = qb + SZ;
    float* vb   = kb + SZ;
    float* obuf = vb + SZ;       // attn out [b][n][h*d]
    float* th   = obuf + SZ;     // tanh(xn@T1.T+b1)
    float* proj = th + SZ;       // attn_out @ Wo.T
    float* lg   = proj + SZ;     // [4096]
    float* gate = lg + NTOK;     // [4096]

    k_ln<<<NTOK, 128, 0, stream>>>(x, ling, linb, xn);
    k_gemm_qkvt<<<dim3(8, 64, 4), 256, 0, stream>>>(xn, Wq, Wk, Wv, Tw1, Tb1,
                                                    qb, kb, vb, th);
    k_tlogit<<<NTOK, 64, 0, stream>>>(th, Tw2, Tb2, lg);
    k_gate<<<2, 1024, 0, stream>>>(lg, gate);
    k_attn<<<dim3(32, 8, 2), 256, 0, stream>>>(qb, kb, vb, obuf);
    k_gemm_proj<<<dim3(8, 64), 256, 0, stream>>>(obuf, Wo, proj);
    k_final<<<NTOK, 128, 0, stream>>>(proj, gate, x, logg, logb, out);
}

// Round 2
// 251.766 us; speedup vs baseline: 2.2183x; 2.2183x over previous
//
#include <hip/hip_runtime.h>
#include <math.h>

#define N_SEQ 2048
#define DM    512
#define NTOK  4096
#define NH    8
#define HD    64

typedef __attribute__((ext_vector_type(8))) short short8;
typedef __attribute__((ext_vector_type(4))) short short4_t;
typedef __attribute__((ext_vector_type(4))) float f32x4;

__device__ inline short f2bf(float x) {
    union { float f; unsigned u; } v; v.f = x;
    unsigned r = v.u + 0x7fff + ((v.u >> 16) & 1);
    return (short)(r >> 16);
}

__device__ inline f32x4 mfma16(short8 a, short8 b, f32x4 c) {
    return __builtin_amdgcn_mfma_f32_16x16x32_bf16(a, b, c, 0, 0, 0);
}

// ---------------- LayerNorm (input) -> bf16 ----------------
__global__ __launch_bounds__(128) void k_ln(const float* __restrict__ x,
                                            const float* __restrict__ g,
                                            const float* __restrict__ b,
                                            short* __restrict__ y) {
    int tk = blockIdx.x, t = threadIdx.x;
    float4 xv = ((const float4*)(x + (size_t)tk * DM))[t];
    float s = xv.x + xv.y + xv.z + xv.w;
    float q = xv.x*xv.x + xv.y*xv.y + xv.z*xv.z + xv.w*xv.w;
    for (int o = 32; o; o >>= 1) { s += __shfl_down(s, o); q += __shfl_down(q, o); }
    __shared__ float ls[2], lq[2];
    if ((t & 63) == 0) { ls[t >> 6] = s; lq[t >> 6] = q; }
    __syncthreads();
    s = ls[0] + ls[1]; q = lq[0] + lq[1];
    float mu = s * (1.f / DM);
    float var = q * (1.f / DM) - mu * mu;
    float rs = rsqrtf(var + 1e-5f);
    float4 gv = ((const float4*)g)[t], bv = ((const float4*)b)[t];
    short4_t o;
    o[0] = f2bf((xv.x - mu) * rs * gv.x + bv.x);
    o[1] = f2bf((xv.y - mu) * rs * gv.y + bv.y);
    o[2] = f2bf((xv.z - mu) * rs * gv.z + bv.z);
    o[3] = f2bf((xv.w - mu) * rs * gv.w + bv.w);
    *(short4_t*)&y[(size_t)tk * DM + t * 4] = o;
}

// ---------------- weight fp32 -> bf16 conversion ----------------
// wcat rows 0..511=Wq, 512..1023=Wk, 1024..1535=Wv, 1536..2047=Tw1; wo separate
__global__ __launch_bounds__(256) void k_cvtw(
    const float* __restrict__ Wq, const float* __restrict__ Wk,
    const float* __restrict__ Wv, const float* __restrict__ Tw1,
    const float* __restrict__ Wo,
    short* __restrict__ wcat, short* __restrict__ wo) {
    int id = blockIdx.x * 256 + threadIdx.x;  // float4 group id
    const float* s; short* d;
    if (id < 262144) {
        int z = id >> 16; int off = id & 65535;
        s = (z == 0) ? Wq : (z == 1) ? Wk : (z == 2) ? Wv : Tw1;
        float4 v = ((const float4*)s)[off];
        d = wcat + (size_t)z * 262144 + (size_t)off * 4;
        short4_t o = {f2bf(v.x), f2bf(v.y), f2bf(v.z), f2bf(v.w)};
        *(short4_t*)d = o;
    } else {
        int off = id - 262144;
        float4 v = ((const float4*)Wo)[off];
        d = wo + (size_t)off * 4;
        short4_t o = {f2bf(v.x), f2bf(v.y), f2bf(v.z), f2bf(v.w)};
        *(short4_t*)d = o;
    }
}

// ---------------- bf16 MFMA NT-GEMM: C = A @ W^T ----------------
// A [M][512] bf16, W [N][512] bf16. 128x128 tile, 4 waves 2x2, BK=32.
// qkvt=1: N=2048, epilogue scatters Q(x0.125)/K/V to [b][h][n][d] bf16, T1->tanh fp32
// qkvt=0: N=512, epilogue writes proj fp32 [M][512]
__global__ __launch_bounds__(256) void k_gemm(
    const short* __restrict__ A, const short* __restrict__ W, int qkvt,
    const float* __restrict__ Tb1,
    short* __restrict__ qb, short* __restrict__ kb, short* __restrict__ vb,
    float* __restrict__ th, float* __restrict__ proj) {
    __shared__ short As[128 * 32];
    __shared__ short Bs[128 * 32];
    int t = threadIdx.x;
    int lane = t & 63, w = t >> 6;
    int wy = w >> 1, wx = w & 1;
    int ln = lane & 15, q4 = lane >> 4;
    int c0 = blockIdx.x * 128, m0 = blockIdx.y * 128;
    f32x4 acc[4][4];
    f32x4 zero = {0.f, 0.f, 0.f, 0.f};
    #pragma unroll
    for (int i = 0; i < 4; i++)
        #pragma unroll
        for (int j = 0; j < 4; j++) acc[i][j] = zero;
    for (int k0 = 0; k0 < DM; k0 += 32) {
        __syncthreads();
        #pragma unroll
        for (int i2 = 0; i2 < 2; i2++) {
            int id = t + 256 * i2;
            int r = id >> 2, c = id & 3;
            *(short8*)&As[r * 32 + c * 8] =
                *(const short8*)&A[(size_t)(m0 + r) * DM + k0 + c * 8];
            *(short8*)&Bs[r * 32 + c * 8] =
                *(const short8*)&W[(size_t)(c0 + r) * DM + k0 + c * 8];
        }
        __syncthreads();
        short8 af[4], bfr[4];
        #pragma unroll
        for (int i = 0; i < 4; i++)
            af[i] = *(short8*)&As[(wy * 64 + i * 16 + ln) * 32 + q4 * 8];
        #pragma unroll
        for (int j = 0; j < 4; j++)
            bfr[j] = *(short8*)&Bs[(wx * 64 + j * 16 + ln) * 32 + q4 * 8];
        #pragma unroll
        for (int i = 0; i < 4; i++)
            #pragma unroll
            for (int j = 0; j < 4; j++)
                acc[i][j] = mfma16(af[i], bfr[j], acc[i][j]);
    }
    if (qkvt) {
        int z = c0 >> 9;  // uniform per block
        if (z < 3) {
            short* dst = (z == 0) ? qb : (z == 1) ? kb : vb;
            float sc = (z == 0) ? 0.125f : 1.0f;
            #pragma unroll
            for (int i = 0; i < 4; i++)
                #pragma unroll
                for (int j = 0; j < 4; j++)
                    #pragma unroll
                    for (int r = 0; r < 4; r++) {
                        int row = m0 + wy * 64 + i * 16 + q4 * 4 + r;
                        int col = c0 + wx * 64 + j * 16 + ln;
                        int nin = col & 511;
                        int h = nin >> 6, d = nin & 63;
                        int bi = row >> 11, n = row & (N_SEQ - 1);
                        dst[(((size_t)bi * NH + h) * N_SEQ + n) * HD + d] =
                            f2bf(acc[i][j][r] * sc);
                    }
        } else {
            #pragma unroll
            for (int i = 0; i < 4; i++)
                #pragma unroll
                for (int j = 0; j < 4; j++)
                    #pragma unroll
                    for (int r = 0; r < 4; r++) {
                        int row = m0 + wy * 64 + i * 16 + q4 * 4 + r;
                        int nin = (c0 + wx * 64 + j * 16 + ln) & 511;
                        th[(size_t)row * DM + nin] = tanhf(acc[i][j][r] + Tb1[nin]);
                    }
        }
    } else {
        #pragma unroll
        for (int i = 0; i < 4; i++)
            #pragma unroll
            for (int j = 0; j < 4; j++)
                #pragma unroll
                for (int r = 0; r < 4; r++) {
                    int row = m0 + wy * 64 + i * 16 + q4 * 4 + r;
                    int col = c0 + wx * 64 + j * 16 + ln;
                    proj[(size_t)row * DM + col] = acc[i][j][r];
                }
    }
}

// ---------------- V transpose: [b][h][n][d] -> [b][h][d][n] (bf16) ----------------
__global__ __launch_bounds__(256) void k_vtr(const short* __restrict__ vb,
                                             short* __restrict__ vtb) {
    __shared__ short tile[64][80];  // 80*2B=160B row stride, 16B-aligned
    int t = threadIdx.x;
    int n0 = blockIdx.x * 64, bh = blockIdx.y;
    const short* src = vb + (size_t)bh * N_SEQ * HD;
    short* dst = vtb + (size_t)bh * HD * N_SEQ;
    #pragma unroll
    for (int i = 0; i < 2; i++) {
        int id = t + 256 * i;
        int r = id >> 3, c = id & 7;
        *(short8*)&tile[r][c * 8] = *(const short8*)&src[(size_t)(n0 + r) * HD + c * 8];
    }
    __syncthreads();
    #pragma unroll
    for (int i = 0; i < 2; i++) {
        int id = t + 256 * i;
        int d = id >> 3, c = id & 7;
        short8 v;
        #pragma unroll
        for (int j = 0; j < 8; j++) v[j] = tile[c * 8 + j][d];
        *(short8*)&dst[(size_t)d * N_SEQ + n0 + c * 8] = v;
    }
}

// ---------------- T logits ----------------
__global__ __launch_bounds__(64) void k_tlogit(const float* __restrict__ th,
                                               const float* __restrict__ w2,
                                               const float* __restrict__ b2,
                                               float* __restrict__ lg) {
    int tk = blockIdx.x, t = threadIdx.x;
    const float* row = th + (size_t)tk * DM;
    float s = 0.f;
    #pragma unroll
    for (int j = 0; j < 8; j++) s += row[t + 64 * j] * w2[t + 64 * j];
    for (int o = 32; o; o >>= 1) s += __shfl_down(s, o);
    if (t == 0) lg[tk] = s + b2[0];
}

// ---------------- gate softmax over sequence ----------------
__global__ __launch_bounds__(1024) void k_gate(const float* __restrict__ lg,
                                               float* __restrict__ gate) {
    int b = blockIdx.x, t = threadIdx.x;
    __shared__ float red[16];
    float v0 = lg[b * N_SEQ + t], v1 = lg[b * N_SEQ + 1024 + t];
    float m = fmaxf(v0, v1);
    for (int o = 32; o; o >>= 1) m = fmaxf(m, __shfl_down(m, o));
    if ((t & 63) == 0) red[t >> 6] = m;
    __syncthreads();
    if (t < 64) {
        float x = (t < 16) ? red[t] : -INFINITY;
        for (int o = 8; o; o >>= 1) x = fmaxf(x, __shfl_down(x, o));
        if (t == 0) red[0] = x;
    }
    __syncthreads();
    float M = red[0];
    float e0 = __expf(v0 - M), e1 = __expf(v1 - M);
    float s = e0 + e1;
    __syncthreads();
    for (int o = 32; o; o >>= 1) s += __shfl_down(s, o);
    if ((t & 63) == 0) red[t >> 6] = s;
    __syncthreads();
    if (t < 64) {
        float x = (t < 16) ? red[t] : 0.f;
        for (int o = 8; o; o >>= 1) x += __shfl_down(x, o);
        if (t == 0) red[0] = x;
    }
    __syncthreads();
    float inv = 1.f / red[0];
    gate[b * N_SEQ + t] = e0 * inv;
    gate[b * N_SEQ + 1024 + t] = e1 * inv;
}

// ---------------- MFMA flash attention ----------------
// grid (32 qtiles, 8 heads, 2 batch), block 256 (4 waves, 16 q-rows each).
// qb,kb bf16 [b][h][n][d] (Q pre-scaled); vtb bf16 [b][h][d][n]; ob bf16 [b][n][512]
__global__ __launch_bounds__(256) void k_attn(const short* __restrict__ qb,
                                              const short* __restrict__ kb,
                                              const short* __restrict__ vtb,
                                              short* __restrict__ ob) {
    __shared__ short Ks[64 * 64];       // [key][d]
    __shared__ short Vt[64 * 64];       // [d][key]
    __shared__ short Pa[4][16 * 64];    // per-wave P in A-operand layout [m][k]
    int t = threadIdx.x;
    int lane = t & 63, w = t >> 6;
    int ln = lane & 15, q4 = lane >> 4;
    int qt = blockIdx.x, h = blockIdx.y, bi = blockIdx.z;
    int q0 = qt * 64;
    int kind = (h < 2) ? 0 : (h < 5) ? 1 : 2;
    int wnd = (h == 2 || h >= 5) ? 64 : (h == 3) ? 128 : (h == 4) ? 256 : 0;
    int dsh = (h == 5) ? 1 : (h == 6) ? 2 : (h == 7) ? 3 : 0;
    int wmax = (kind == 0) ? (1 << 29) : (wnd << dsh);
    int dmask = (1 << dsh) - 1;
    const size_t base = ((size_t)bi * NH + h) * N_SEQ * HD;
    const short* Q = qb + base;
    const short* K = kb + base;
    const short* Vg = vtb + base;  // [d][n]
    // Q fragments in registers (A-operand layout, rows w*16+ln)
    short8 qa[2];
    {
        const short* qrow = Q + (size_t)(q0 + w * 16 + ln) * HD + q4 * 8;
        qa[0] = *(const short8*)qrow;
        qa[1] = *(const short8*)(qrow + 32);
    }
    float m_i[4], l_i[4];
    f32x4 O[4];
    f32x4 zero = {0.f, 0.f, 0.f, 0.f};
    #pragma unroll
    for (int r = 0; r < 4; r++) { m_i[r] = -1e30f; l_i[r] = 0.f; }
    #pragma unroll
    for (int d = 0; d < 4; d++) O[d] = zero;
    int kmin = q0 - wmax; if (kmin < 0) kmin = 0;
    int kmax = q0 + 63 + wmax; if (kmax > N_SEQ - 1) kmax = N_SEQ - 1;
    short* Paw = Pa[w];
    for (int kt = kmin >> 6; kt <= (kmax >> 6); kt++) {
        int k0 = kt << 6;
        __syncthreads();  // prior tile reads done
        #pragma unroll
        for (int i2 = 0; i2 < 2; i2++) {
            int id = t + 256 * i2;
            int r = id >> 3, c = id & 7;
            *(short8*)&Ks[r * 64 + c * 8] =
                *(const short8*)&K[(size_t)(k0 + r) * HD + c * 8];
            *(short8*)&Vt[r * 64 + c * 8] =
                *(const short8*)&Vg[(size_t)r * N_SEQ + k0 + c * 8];
        }
        __syncthreads();
        // S = Q K^T
        f32x4 S[4];
        #pragma unroll
        for (int nt = 0; nt < 4; nt++) S[nt] = zero;
        #pragma unroll
        for (int nt = 0; nt < 4; nt++) {
            #pragma unroll
            for (int ks = 0; ks < 2; ks++) {
                short8 bfr = *(short8*)&Ks[(nt * 16 + ln) * 64 + ks * 32 + q4 * 8];
                S[nt] = mfma16(qa[ks], bfr, S[nt]);
            }
        }
        // mask + online softmax; write P to per-wave LDS in A-layout
        int qi_base = q0 + w * 16 + q4 * 4;
        #pragma unroll
        for (int r = 0; r < 4; r++) {
            int qi = qi_base + r;
            float sv[4]; int vld[4];
            #pragma unroll
            for (int nt = 0; nt < 4; nt++) {
                int kj = k0 + nt * 16 + ln;
                int dlt = qi - kj; dlt = (dlt < 0) ? -dlt : dlt;
                int valid;
                if (kind == 0) valid = 1;
                else if (kind == 1) valid = (dlt <= wnd);
                else valid = ((dlt & dmask) == 0) && ((dlt >> dsh) <= wnd);
                vld[nt] = valid;
                sv[nt] = valid ? S[nt][r] : -1e30f;
            }
            float rm = fmaxf(fmaxf(sv[0], sv[1]), fmaxf(sv[2], sv[3]));
            rm = fmaxf(rm, __shfl_xor(rm, 1));
            rm = fmaxf(rm, __shfl_xor(rm, 2));
            rm = fmaxf(rm, __shfl_xor(rm, 4));
            rm = fmaxf(rm, __shfl_xor(rm, 8));
            float mn = fmaxf(m_i[r], rm);
            float sc = __expf(m_i[r] - mn);
            float rs = 0.f;
            #pragma unroll
            for (int nt = 0; nt < 4; nt++) {
                float p = vld[nt] ? __expf(sv[nt] - mn) : 0.f;
                Paw[(q4 * 4 + r) * 64 + nt * 16 + ln] = f2bf(p);
                rs += p;
            }
            rs += __shfl_xor(rs, 1);
            rs += __shfl_xor(rs, 2);
            rs += __shfl_xor(rs, 4);
            rs += __shfl_xor(rs, 8);
            l_i[r] = l_i[r] * sc + rs;
            m_i[r] = mn;
            #pragma unroll
            for (int d = 0; d < 4; d++) O[d][r] *= sc;
        }
        // O += P V   (P from own wave's LDS buffer; compiler inserts lgkmcnt waits)
        short8 pf[2];
        pf[0] = *(short8*)&Paw[ln * 64 + q4 * 8];
        pf[1] = *(short8*)&Paw[ln * 64 + 32 + q4 * 8];
        #pragma unroll
        for (int dt = 0; dt < 4; dt++) {
            #pragma unroll
            for (int ks = 0; ks < 2; ks++) {
                short8 bfr = *(short8*)&Vt[(dt * 16 + ln) * 64 + ks * 32 + q4 * 8];
                O[dt] = mfma16(pf[ks], bfr, O[dt]);
            }
        }
    }
    // epilogue
    #pragma unroll
    for (int r = 0; r < 4; r++) {
        float inv = 1.f / l_i[r];
        int n = q0 + w * 16 + q4 * 4 + r;
        #pragma unroll
        for (int dt = 0; dt < 4; dt++)
            ob[((size_t)bi * N_SEQ + n) * DM + h * 64 + dt * 16 + ln] =
                f2bf(O[dt][r] * inv);
    }
}

// ---------------- final: y = proj*gate + x0 ; LN_out ----------------
__global__ __launch_bounds__(128) void k_final(const float* __restrict__ proj,
                                               const float* __restrict__ gate,
                                               const float* __restrict__ x0,
                                               const float* __restrict__ g,
                                               const float* __restrict__ b,
                                               float* __restrict__ out) {
    int tk = blockIdx.x, t = threadIdx.x;
    float gt = gate[tk];
    float4 pv = ((const float4*)(proj + (size_t)tk * DM))[t];
    float4 xv = ((const float4*)(x0 + (size_t)tk * DM))[t];
    float4 y;
    y.x = pv.x * gt + xv.x;
    y.y = pv.y * gt + xv.y;
    y.z = pv.z * gt + xv.z;
    y.w = pv.w * gt + xv.w;
    float s = y.x + y.y + y.z + y.w;
    float q = y.x*y.x + y.y*y.y + y.z*y.z + y.w*y.w;
    for (int o = 32; o; o >>= 1) { s += __shfl_down(s, o); q += __shfl_down(q, o); }
    __shared__ float ls[2], lq[2];
    if ((t & 63) == 0) { ls[t >> 6] = s; lq[t >> 6] = q; }
    __syncthreads();
    s = ls[0] + ls[1]; q = lq[0] + lq[1];
    float mu = s * (1.f / DM);
    float var = q * (1.f / DM) - mu * mu;
    float rs = rsqrtf(var + 1e-5f);
    float4 gv = ((const float4*)g)[t], bv = ((const float4*)b)[t];
    float4 o;
    o.x = (y.x - mu) * rs * gv.x + bv.x;
    o.y = (y.y - mu) * rs * gv.y + bv.y;
    o.z = (y.z - mu) * rs * gv.z + bv.z;
    o.w = (y.w - mu) * rs * gv.w + bv.w;
    ((float4*)(out + (size_t)tk * DM))[t] = o;
}

extern "C" void kernel_launch(void* const* d_in, const int* in_sizes, int n_in,
                              void* d_out, int out_size, void* d_ws, size_t ws_size,
                              hipStream_t stream) {
    (void)in_sizes; (void)n_in; (void)out_size; (void)ws_size;
    const float* x    = (const float*)d_in[0];
    const float* Wq   = (const float*)d_in[1];
    const float* Wk   = (const float*)d_in[2];
    const float* Wv   = (const float*)d_in[3];
    const float* Wo   = (const float*)d_in[4];
    const float* Tw1  = (const float*)d_in[5];
    const float* Tb1  = (const float*)d_in[6];
    const float* Tw2  = (const float*)d_in[7];
    const float* Tb2  = (const float*)d_in[8];
    const float* ling = (const float*)d_in[9];
    const float* linb = (const float*)d_in[10];
    const float* logg = (const float*)d_in[11];
    const float* logb = (const float*)d_in[12];
    float* out = (float*)d_out;

    const size_t SZ = (size_t)NTOK * DM;  // 2,097,152 elems
    char* p = (char*)d_ws;
    short* xn   = (short*)p; p += SZ * 2;               // bf16 LN(x)
    short* wcat = (short*)p; p += (size_t)2048 * DM * 2; // bf16 [Wq;Wk;Wv;Tw1]
    short* wo   = (short*)p; p += (size_t)DM * DM * 2;   // bf16 Wo
    short* qb   = (short*)p; p += SZ * 2;               // bf16 [b][h][n][d] (x0.125)
    short* kb   = (short*)p; p += SZ * 2;
    short* vb   = (short*)p; p += SZ * 2;
    short* vtb  = (short*)p; p += SZ * 2;               // bf16 [b][h][d][n]
    short* obuf = (short*)p; p += SZ * 2;               // bf16 attn out [b][n][512]
    float* th   = (float*)p; p += SZ * 4;               // fp32 tanh(xn@T1+b1)
    float* proj = (float*)p; p += SZ * 4;               // fp32 attn@Wo^T
    float* lg   = (float*)p; p += (size_t)NTOK * 4;
    float* gate = (float*)p; p += (size_t)NTOK * 4;

    k_ln<<<NTOK, 128, 0, stream>>>(x, ling, linb, xn);
    k_cvtw<<<1280, 256, 0, stream>>>(Wq, Wk, Wv, Tw1, Wo, wcat, wo);
    k_gemm<<<dim3(16, 32), 256, 0, stream>>>(xn, wcat, 1, Tb1, qb, kb, vb, th, nullptr);
    k_vtr<<<dim3(32, 16), 256, 0, stream>>>(vb, vtb);
    k_tlogit<<<NTOK, 64, 0, stream>>>(th, Tw2, Tb2, lg);
    k_gate<<<2, 1024, 0, stream>>>(lg, gate);
    k_attn<<<dim3(32, 8, 2), 256, 0, stream>>>(qb, kb, vtb, obuf);
    k_gemm<<<dim3(4, 32), 256, 0, stream>>>(obuf, wo, 0, nullptr,
                                            nullptr, nullptr, nullptr, nullptr, proj);
    k_final<<<NTOK, 128, 0, stream>>>(proj, gate, x, logg, logb, out);
}

// Round 3
// 195.831 us; speedup vs baseline: 2.8519x; 1.2856x over previous
//
#include <hip/hip_runtime.h>
#include <math.h>

#define N_SEQ 2048
#define DM    512
#define NTOK  4096
#define NH    8
#define HD    64
#define NSLOT 25
#define CHUNK 5

typedef __attribute__((ext_vector_type(8))) short short8;
typedef __attribute__((ext_vector_type(4))) short short4_t;
typedef __attribute__((ext_vector_type(4))) float f32x4;

__device__ inline short f2bf(float x) {
    union { float f; unsigned u; } v; v.f = x;
    unsigned r = v.u + 0x7fff + ((v.u >> 16) & 1);
    return (short)(r >> 16);
}
__device__ inline float bf2f(short s) {
    union { unsigned u; float f; } v; v.u = ((unsigned)(unsigned short)s) << 16;
    return v.f;
}

__device__ inline f32x4 mfma16(short8 a, short8 b, f32x4 c) {
    return __builtin_amdgcn_mfma_f32_16x16x32_bf16(a, b, c, 0, 0, 0);
}

__device__ __forceinline__ void async_cp16(const short* g, short* l) {
    __builtin_amdgcn_global_load_lds(
        (const __attribute__((address_space(1))) void*)g,
        (__attribute__((address_space(3))) void*)l, 16, 0, 0);
}

// ---------------- LayerNorm (input) -> bf16 ----------------
__global__ __launch_bounds__(128) void k_ln(const float* __restrict__ x,
                                            const float* __restrict__ g,
                                            const float* __restrict__ b,
                                            short* __restrict__ y) {
    int tk = blockIdx.x, t = threadIdx.x;
    float4 xv = ((const float4*)(x + (size_t)tk * DM))[t];
    float s = xv.x + xv.y + xv.z + xv.w;
    float q = xv.x*xv.x + xv.y*xv.y + xv.z*xv.z + xv.w*xv.w;
    for (int o = 32; o; o >>= 1) { s += __shfl_down(s, o); q += __shfl_down(q, o); }
    __shared__ float ls[2], lq[2];
    if ((t & 63) == 0) { ls[t >> 6] = s; lq[t >> 6] = q; }
    __syncthreads();
    s = ls[0] + ls[1]; q = lq[0] + lq[1];
    float mu = s * (1.f / DM);
    float var = q * (1.f / DM) - mu * mu;
    float rs = rsqrtf(var + 1e-5f);
    float4 gv = ((const float4*)g)[t], bv = ((const float4*)b)[t];
    short4_t o;
    o[0] = f2bf((xv.x - mu) * rs * gv.x + bv.x);
    o[1] = f2bf((xv.y - mu) * rs * gv.y + bv.y);
    o[2] = f2bf((xv.z - mu) * rs * gv.z + bv.z);
    o[3] = f2bf((xv.w - mu) * rs * gv.w + bv.w);
    *(short4_t*)&y[(size_t)tk * DM + t * 4] = o;
}

// ---------------- weight fp32 -> bf16 ----------------
__global__ __launch_bounds__(256) void k_cvtw(
    const float* __restrict__ Wq, const float* __restrict__ Wk,
    const float* __restrict__ Wv, const float* __restrict__ Tw1,
    const float* __restrict__ Wo,
    short* __restrict__ wcat, short* __restrict__ wo) {
    int id = blockIdx.x * 256 + threadIdx.x;
    if (id < 262144) {
        int z = id >> 16; int off = id & 65535;
        const float* s = (z == 0) ? Wq : (z == 1) ? Wk : (z == 2) ? Wv : Tw1;
        float4 v = ((const float4*)s)[off];
        short4_t o = {f2bf(v.x), f2bf(v.y), f2bf(v.z), f2bf(v.w)};
        *(short4_t*)(wcat + (size_t)z * 262144 + (size_t)off * 4) = o;
    } else {
        int off = id - 262144;
        float4 v = ((const float4*)Wo)[off];
        short4_t o = {f2bf(v.x), f2bf(v.y), f2bf(v.z), f2bf(v.w)};
        *(short4_t*)(wo + (size_t)off * 4) = o;
    }
}

// ---------------- bf16 MFMA NT-GEMM: C = A @ W^T ----------------
__global__ __launch_bounds__(256) void k_gemm(
    const short* __restrict__ A, const short* __restrict__ W, int qkvt,
    const float* __restrict__ Tb1,
    short* __restrict__ qb, short* __restrict__ kb, short* __restrict__ vb,
    float* __restrict__ th, float* __restrict__ proj) {
    __shared__ short As[128 * 32];
    __shared__ short Bs[128 * 32];
    int t = threadIdx.x;
    int lane = t & 63, w = t >> 6;
    int wy = w >> 1, wx = w & 1;
    int ln = lane & 15, q4 = lane >> 4;
    int c0 = blockIdx.x * 128, m0 = blockIdx.y * 128;
    int sr = t >> 2, sc = (t & 3) << 3;   // staging: 16B per thread
    f32x4 acc[4][4];
    f32x4 zero = {0.f, 0.f, 0.f, 0.f};
    #pragma unroll
    for (int i = 0; i < 4; i++)
        #pragma unroll
        for (int j = 0; j < 4; j++) acc[i][j] = zero;
    for (int k0 = 0; k0 < DM; k0 += 32) {
        __syncthreads();
        async_cp16(&A[(size_t)(m0 + sr) * DM + k0 + sc],      &As[sr * 32 + sc]);
        async_cp16(&A[(size_t)(m0 + 64 + sr) * DM + k0 + sc], &As[(64 + sr) * 32 + sc]);
        async_cp16(&W[(size_t)(c0 + sr) * DM + k0 + sc],      &Bs[sr * 32 + sc]);
        async_cp16(&W[(size_t)(c0 + 64 + sr) * DM + k0 + sc], &Bs[(64 + sr) * 32 + sc]);
        __syncthreads();
        short8 af[4], bfr[4];
        #pragma unroll
        for (int i = 0; i < 4; i++)
            af[i] = *(short8*)&As[(wy * 64 + i * 16 + ln) * 32 + q4 * 8];
        #pragma unroll
        for (int j = 0; j < 4; j++)
            bfr[j] = *(short8*)&Bs[(wx * 64 + j * 16 + ln) * 32 + q4 * 8];
        #pragma unroll
        for (int i = 0; i < 4; i++)
            #pragma unroll
            for (int j = 0; j < 4; j++)
                acc[i][j] = mfma16(af[i], bfr[j], acc[i][j]);
    }
    if (qkvt) {
        int z = c0 >> 9;
        if (z < 3) {
            short* dst = (z == 0) ? qb : (z == 1) ? kb : vb;
            float sc2 = (z == 0) ? 0.125f : 1.0f;
            #pragma unroll
            for (int i = 0; i < 4; i++)
                #pragma unroll
                for (int j = 0; j < 4; j++)
                    #pragma unroll
                    for (int r = 0; r < 4; r++) {
                        int row = m0 + wy * 64 + i * 16 + q4 * 4 + r;
                        int col = c0 + wx * 64 + j * 16 + ln;
                        int nin = col & 511;
                        int h = nin >> 6, d = nin & 63;
                        int bi = row >> 11, n = row & (N_SEQ - 1);
                        dst[(((size_t)bi * NH + h) * N_SEQ + n) * HD + d] =
                            f2bf(acc[i][j][r] * sc2);
                    }
        } else {
            #pragma unroll
            for (int i = 0; i < 4; i++)
                #pragma unroll
                for (int j = 0; j < 4; j++)
                    #pragma unroll
                    for (int r = 0; r < 4; r++) {
                        int row = m0 + wy * 64 + i * 16 + q4 * 4 + r;
                        int nin = (c0 + wx * 64 + j * 16 + ln) & 511;
                        th[(size_t)row * DM + nin] = tanhf(acc[i][j][r] + Tb1[nin]);
                    }
        }
    } else {
        #pragma unroll
        for (int i = 0; i < 4; i++)
            #pragma unroll
            for (int j = 0; j < 4; j++)
                #pragma unroll
                for (int r = 0; r < 4; r++) {
                    int row = m0 + wy * 64 + i * 16 + q4 * 4 + r;
                    int col = c0 + wx * 64 + j * 16 + ln;
                    proj[(size_t)row * DM + col] = acc[i][j][r];
                }
    }
}

// ---------------- V transpose: [b][h][n][d] -> [b][h][d][n] ----------------
__global__ __launch_bounds__(256) void k_vtr(const short* __restrict__ vb,
                                             short* __restrict__ vtb) {
    __shared__ short tile[64][80];
    int t = threadIdx.x;
    int n0 = blockIdx.x * 64, bh = blockIdx.y;
    const short* src = vb + (size_t)bh * N_SEQ * HD;
    short* dst = vtb + (size_t)bh * HD * N_SEQ;
    #pragma unroll
    for (int i = 0; i < 2; i++) {
        int id = t + 256 * i;
        int r = id >> 3, c = id & 7;
        *(short8*)&tile[r][c * 8] = *(const short8*)&src[(size_t)(n0 + r) * HD + c * 8];
    }
    __syncthreads();
    #pragma unroll
    for (int i = 0; i < 2; i++) {
        int id = t + 256 * i;
        int d = id >> 3, c = id & 7;
        short8 v;
        #pragma unroll
        for (int j = 0; j < 8; j++) v[j] = tile[c * 8 + j][d];
        *(short8*)&dst[(size_t)d * N_SEQ + n0 + c * 8] = v;
    }
}

// ---------------- T logits ----------------
__global__ __launch_bounds__(64) void k_tlogit(const float* __restrict__ th,
                                               const float* __restrict__ w2,
                                               const float* __restrict__ b2,
                                               float* __restrict__ lg) {
    int tk = blockIdx.x, t = threadIdx.x;
    const float* row = th + (size_t)tk * DM;
    float s = 0.f;
    #pragma unroll
    for (int j = 0; j < 8; j++) s += row[t + 64 * j] * w2[t + 64 * j];
    for (int o = 32; o; o >>= 1) s += __shfl_down(s, o);
    if (t == 0) lg[tk] = s + b2[0];
}

// ---------------- gate softmax over sequence ----------------
__global__ __launch_bounds__(1024) void k_gate(const float* __restrict__ lg,
                                               float* __restrict__ gate) {
    int b = blockIdx.x, t = threadIdx.x;
    __shared__ float red[16];
    float v0 = lg[b * N_SEQ + t], v1 = lg[b * N_SEQ + 1024 + t];
    float m = fmaxf(v0, v1);
    for (int o = 32; o; o >>= 1) m = fmaxf(m, __shfl_down(m, o));
    if ((t & 63) == 0) red[t >> 6] = m;
    __syncthreads();
    if (t < 64) {
        float x = (t < 16) ? red[t] : -INFINITY;
        for (int o = 8; o; o >>= 1) x = fmaxf(x, __shfl_down(x, o));
        if (t == 0) red[0] = x;
    }
    __syncthreads();
    float M = red[0];
    float e0 = __expf(v0 - M), e1 = __expf(v1 - M);
    float s = e0 + e1;
    __syncthreads();
    for (int o = 32; o; o >>= 1) s += __shfl_down(s, o);
    if ((t & 63) == 0) red[t >> 6] = s;
    __syncthreads();
    if (t < 64) {
        float x = (t < 16) ? red[t] : 0.f;
        for (int o = 8; o; o >>= 1) x += __shfl_down(x, o);
        if (t == 0) red[0] = x;
    }
    __syncthreads();
    float inv = 1.f / red[0];
    gate[b * N_SEQ + t] = e0 * inv;
    gate[b * N_SEQ + 1024 + t] = e1 * inv;
}

// ---------------- split-K MFMA flash attention ----------------
// grid (25 chunk-slots, 32 qtiles, 2 batch), block 256.
// Writes unnormalized partial O (bf16) + per-row m,l (fp32).
__global__ __launch_bounds__(256) void k_attn(const short* __restrict__ qb,
                                              const short* __restrict__ kb,
                                              const short* __restrict__ vtb,
                                              short* __restrict__ P_O,
                                              float* __restrict__ P_ml) {
    __shared__ short Ks[64 * 64];
    __shared__ short Vt[64 * 64];
    __shared__ short Pa[4][16 * 64];
    int t = threadIdx.x;
    int lane = t & 63, w = t >> 6;
    int ln = lane & 15, q4 = lane >> 4;
    int slot = blockIdx.x, qt = blockIdx.y, bi = blockIdx.z;
    int q0 = qt * 64;
    int h, c;
    if (slot < 7)        { h = 0; c = slot; }
    else if (slot < 14)  { h = 1; c = slot - 7; }
    else if (slot == 14) { h = 2; c = 0; }
    else if (slot == 15) { h = 3; c = 0; }
    else if (slot < 18)  { h = 4; c = slot - 16; }
    else if (slot == 18) { h = 5; c = 0; }
    else if (slot < 21)  { h = 6; c = slot - 19; }
    else                 { h = 7; c = slot - 21; }
    int kind = (h < 2) ? 0 : (h < 5) ? 1 : 2;
    int wnd = (h == 2 || h >= 5) ? 64 : (h == 3) ? 128 : (h == 4) ? 256 : 0;
    int dsh = (h == 5) ? 1 : (h == 6) ? 2 : (h == 7) ? 3 : 0;
    int dmask = (1 << dsh) - 1;
    int wmax = (kind == 0) ? 0 : (wnd << dsh);
    int tLoU, tHiU;
    if (kind == 0) { tLoU = 0; tHiU = 31; }
    else { tLoU = (q0 - wmax) >> 6; tHiU = (q0 + 63 + wmax) >> 6; }
    int ktLo = tLoU + c * CHUNK;
    int ktHi = ktLo + CHUNK - 1;
    if (ktHi > tHiU) ktHi = tHiU;
    if (ktHi > 31) ktHi = 31;
    if (ktLo < 0) ktLo = 0;
    int p = (bi * 32 + qt) * NSLOT + slot;
    float* ml = P_ml + (size_t)p * 128;
    if (ktLo > ktHi) {
        if (t < 64) { ml[t] = -1e30f; ml[64 + t] = 0.f; }
        return;
    }
    const size_t base = ((size_t)bi * NH + h) * N_SEQ * HD;
    const short* Q = qb + base;
    const short* K = kb + base;
    const short* Vg = vtb + base;
    short8 qa[2];
    {
        const short* qrow = Q + (size_t)(q0 + w * 16 + ln) * HD + q4 * 8;
        qa[0] = *(const short8*)qrow;
        qa[1] = *(const short8*)(qrow + 32);
    }
    float m_i[4], l_i[4];
    f32x4 O[4];
    f32x4 zero = {0.f, 0.f, 0.f, 0.f};
    #pragma unroll
    for (int r = 0; r < 4; r++) { m_i[r] = -1e30f; l_i[r] = 0.f; }
    #pragma unroll
    for (int d = 0; d < 4; d++) O[d] = zero;
    short* Paw = Pa[w];
    for (int kt = ktLo; kt <= ktHi; kt++) {
        int k0 = kt << 6;
        __syncthreads();
        #pragma unroll
        for (int i2 = 0; i2 < 2; i2++) {
            int id = t + 256 * i2;
            int r = id >> 3, cc = id & 7;
            *(short8*)&Ks[r * 64 + cc * 8] =
                *(const short8*)&K[(size_t)(k0 + r) * HD + cc * 8];
            *(short8*)&Vt[r * 64 + cc * 8] =
                *(const short8*)&Vg[(size_t)r * N_SEQ + k0 + cc * 8];
        }
        __syncthreads();
        f32x4 S[4];
        #pragma unroll
        for (int nt = 0; nt < 4; nt++) S[nt] = zero;
        #pragma unroll
        for (int nt = 0; nt < 4; nt++) {
            #pragma unroll
            for (int ks = 0; ks < 2; ks++) {
                short8 bfr = *(short8*)&Ks[(nt * 16 + ln) * 64 + ks * 32 + q4 * 8];
                S[nt] = mfma16(qa[ks], bfr, S[nt]);
            }
        }
        int qi_base = q0 + w * 16 + q4 * 4;
        #pragma unroll
        for (int r = 0; r < 4; r++) {
            int qi = qi_base + r;
            float sv[4]; int vld[4];
            #pragma unroll
            for (int nt = 0; nt < 4; nt++) {
                int kj = k0 + nt * 16 + ln;
                int dlt = qi - kj; dlt = (dlt < 0) ? -dlt : dlt;
                int valid;
                if (kind == 0) valid = 1;
                else if (kind == 1) valid = (dlt <= wnd);
                else valid = ((dlt & dmask) == 0) && ((dlt >> dsh) <= wnd);
                vld[nt] = valid;
                sv[nt] = valid ? S[nt][r] : -1e30f;
            }
            float rm = fmaxf(fmaxf(sv[0], sv[1]), fmaxf(sv[2], sv[3]));
            rm = fmaxf(rm, __shfl_xor(rm, 1));
            rm = fmaxf(rm, __shfl_xor(rm, 2));
            rm = fmaxf(rm, __shfl_xor(rm, 4));
            rm = fmaxf(rm, __shfl_xor(rm, 8));
            float mn = fmaxf(m_i[r], rm);
            float sc = __expf(m_i[r] - mn);
            float rs = 0.f;
            #pragma unroll
            for (int nt = 0; nt < 4; nt++) {
                float pp = vld[nt] ? __expf(sv[nt] - mn) : 0.f;
                Paw[(q4 * 4 + r) * 64 + nt * 16 + ln] = f2bf(pp);
                rs += pp;
            }
            rs += __shfl_xor(rs, 1);
            rs += __shfl_xor(rs, 2);
            rs += __shfl_xor(rs, 4);
            rs += __shfl_xor(rs, 8);
            l_i[r] = l_i[r] * sc + rs;
            m_i[r] = mn;
            #pragma unroll
            for (int d = 0; d < 4; d++) O[d][r] *= sc;
        }
        short8 pf[2];
        pf[0] = *(short8*)&Paw[ln * 64 + q4 * 8];
        pf[1] = *(short8*)&Paw[ln * 64 + 32 + q4 * 8];
        #pragma unroll
        for (int dt = 0; dt < 4; dt++) {
            #pragma unroll
            for (int ks = 0; ks < 2; ks++) {
                short8 bfr = *(short8*)&Vt[(dt * 16 + ln) * 64 + ks * 32 + q4 * 8];
                O[dt] = mfma16(pf[ks], bfr, O[dt]);
            }
        }
    }
    short* Op = P_O + (size_t)p * 4096;
    #pragma unroll
    for (int r = 0; r < 4; r++) {
        int row = w * 16 + q4 * 4 + r;
        if (ln == 0) { ml[row] = m_i[r]; ml[64 + row] = l_i[r]; }
        #pragma unroll
        for (int dt = 0; dt < 4; dt++)
            Op[row * 64 + dt * 16 + ln] = f2bf(O[dt][r]);
    }
}

// ---------------- combine partials -> obuf [b][n][512] bf16 ----------------
__global__ __launch_bounds__(256) void k_combine(const short* __restrict__ P_O,
                                                 const float* __restrict__ P_ml,
                                                 short* __restrict__ ob) {
    const int hbase[8] = {0, 7, 14, 15, 16, 18, 19, 21};
    const int hcnt[8]  = {7, 7, 1, 1, 2, 1, 2, 4};
    int h = blockIdx.x, qt = blockIdx.y, bi = blockIdx.z;
    int t = threadIdx.x;
    int row = t >> 2, c0 = (t & 3) * 16;
    int pb = (bi * 32 + qt) * NSLOT + hbase[h];
    int cnt = hcnt[h];
    float m = -1e30f;
    for (int s = 0; s < cnt; s++)
        m = fmaxf(m, P_ml[(size_t)(pb + s) * 128 + row]);
    float l = 0.f;
    float acc[16];
    #pragma unroll
    for (int j = 0; j < 16; j++) acc[j] = 0.f;
    for (int s = 0; s < cnt; s++) {
        float ms = P_ml[(size_t)(pb + s) * 128 + row];
        float ls = P_ml[(size_t)(pb + s) * 128 + 64 + row];
        if (ls > 0.f) {
            float sc = __expf(ms - m);
            l += ls * sc;
            const short* Op = P_O + (size_t)(pb + s) * 4096 + row * 64 + c0;
            short8 v0 = *(const short8*)Op;
            short8 v1 = *(const short8*)(Op + 8);
            #pragma unroll
            for (int j = 0; j < 8; j++) acc[j]     += bf2f(v0[j]) * sc;
            #pragma unroll
            for (int j = 0; j < 8; j++) acc[8 + j] += bf2f(v1[j]) * sc;
        }
    }
    float inv = 1.f / l;
    int n = qt * 64 + row;
    short8 o0, o1;
    #pragma unroll
    for (int j = 0; j < 8; j++) o0[j] = f2bf(acc[j] * inv);
    #pragma unroll
    for (int j = 0; j < 8; j++) o1[j] = f2bf(acc[8 + j] * inv);
    short* dst = ob + ((size_t)bi * N_SEQ + n) * DM + h * 64 + c0;
    *(short8*)dst = o0;
    *(short8*)(dst + 8) = o1;
}

// ---------------- final: y = proj*gate + x0 ; LN_out ----------------
__global__ __launch_bounds__(128) void k_final(const float* __restrict__ proj,
                                               const float* __restrict__ gate,
                                               const float* __restrict__ x0,
                                               const float* __restrict__ g,
                                               const float* __restrict__ b,
                                               float* __restrict__ out) {
    int tk = blockIdx.x, t = threadIdx.x;
    float gt = gate[tk];
    float4 pv = ((const float4*)(proj + (size_t)tk * DM))[t];
    float4 xv = ((const float4*)(x0 + (size_t)tk * DM))[t];
    float4 y;
    y.x = pv.x * gt + xv.x;
    y.y = pv.y * gt + xv.y;
    y.z = pv.z * gt + xv.z;
    y.w = pv.w * gt + xv.w;
    float s = y.x + y.y + y.z + y.w;
    float q = y.x*y.x + y.y*y.y + y.z*y.z + y.w*y.w;
    for (int o = 32; o; o >>= 1) { s += __shfl_down(s, o); q += __shfl_down(q, o); }
    __shared__ float ls[2], lq[2];
    if ((t & 63) == 0) { ls[t >> 6] = s; lq[t >> 6] = q; }
    __syncthreads();
    s = ls[0] + ls[1]; q = lq[0] + lq[1];
    float mu = s * (1.f / DM);
    float var = q * (1.f / DM) - mu * mu;
    float rs = rsqrtf(var + 1e-5f);
    float4 gv = ((const float4*)g)[t], bv = ((const float4*)b)[t];
    float4 o;
    o.x = (y.x - mu) * rs * gv.x + bv.x;
    o.y = (y.y - mu) * rs * gv.y + bv.y;
    o.z = (y.z - mu) * rs * gv.z + bv.z;
    o.w = (y.w - mu) * rs * gv.w + bv.w;
    ((float4*)(out + (size_t)tk * DM))[t] = o;
}

extern "C" void kernel_launch(void* const* d_in, const int* in_sizes, int n_in,
                              void* d_out, int out_size, void* d_ws, size_t ws_size,
                              hipStream_t stream) {
    (void)in_sizes; (void)n_in; (void)out_size; (void)ws_size;
    const float* x    = (const float*)d_in[0];
    const float* Wq   = (const float*)d_in[1];
    const float* Wk   = (const float*)d_in[2];
    const float* Wv   = (const float*)d_in[3];
    const float* Wo   = (const float*)d_in[4];
    const float* Tw1  = (const float*)d_in[5];
    const float* Tb1  = (const float*)d_in[6];
    const float* Tw2  = (const float*)d_in[7];
    const float* Tb2  = (const float*)d_in[8];
    const float* ling = (const float*)d_in[9];
    const float* linb = (const float*)d_in[10];
    const float* logg = (const float*)d_in[11];
    const float* logb = (const float*)d_in[12];
    float* out = (float*)d_out;

    const size_t SZ = (size_t)NTOK * DM;
    const int NPART = 2 * 32 * NSLOT;  // 1600 partial tiles
    char* p = (char*)d_ws;
    short* xn   = (short*)p; p += SZ * 2;
    short* wcat = (short*)p; p += (size_t)2048 * DM * 2;
    short* wo   = (short*)p; p += (size_t)DM * DM * 2;
    short* qb   = (short*)p; p += SZ * 2;
    short* kb   = (short*)p; p += SZ * 2;
    short* vb   = (short*)p; p += SZ * 2;
    short* vtb  = (short*)p; p += SZ * 2;
    short* obuf = (short*)p; p += SZ * 2;
    float* th   = (float*)p; p += SZ * 4;
    float* lg   = (float*)p; p += (size_t)NTOK * 4;
    float* gate = (float*)p; p += (size_t)NTOK * 4;
    float* P_ml = (float*)p; p += (size_t)NPART * 128 * 4;
    // proj (8 MB fp32) and P_O (12.8 MB bf16) share this region:
    // P_O is dead after k_combine; proj is written only by the later Wo GEMM.
    float* proj = (float*)p;
    short* P_O  = (short*)p; p += (size_t)NPART * 4096 * 2;

    k_ln<<<NTOK, 128, 0, stream>>>(x, ling, linb, xn);
    k_cvtw<<<1280, 256, 0, stream>>>(Wq, Wk, Wv, Tw1, Wo, wcat, wo);
    k_gemm<<<dim3(16, 32), 256, 0, stream>>>(xn, wcat, 1, Tb1, qb, kb, vb, th, nullptr);
    k_vtr<<<dim3(32, 16), 256, 0, stream>>>(vb, vtb);
    k_tlogit<<<NTOK, 64, 0, stream>>>(th, Tw2, Tb2, lg);
    k_gate<<<2, 1024, 0, stream>>>(lg, gate);
    k_attn<<<dim3(NSLOT, 32, 2), 256, 0, stream>>>(qb, kb, vtb, P_O, P_ml);
    k_combine<<<dim3(8, 32, 2), 256, 0, stream>>>(P_O, P_ml, obuf);
    k_gemm<<<dim3(4, 32), 256, 0, stream>>>(obuf, wo, 0, nullptr,
                                            nullptr, nullptr, nullptr, nullptr, proj);
    k_final<<<NTOK, 128, 0, stream>>>(proj, gate, x, logg, logb, out);
}

// Round 4
// 173.912 us; speedup vs baseline: 3.2114x; 1.1260x over previous
//
#include <hip/hip_runtime.h>
#include <math.h>

#define N_SEQ 2048
#define DM    512
#define NTOK  4096
#define NH    8
#define HD    64
#define NSLOT 25
#define CHUNK 5

typedef __attribute__((ext_vector_type(8))) short short8;
typedef __attribute__((ext_vector_type(4))) short short4_t;
typedef __attribute__((ext_vector_type(4))) float f32x4;

__device__ inline short f2bf(float x) {
    union { float f; unsigned u; } v; v.f = x;
    unsigned r = v.u + 0x7fff + ((v.u >> 16) & 1);
    return (short)(r >> 16);
}
__device__ inline float bf2f(short s) {
    union { unsigned u; float f; } v; v.u = ((unsigned)(unsigned short)s) << 16;
    return v.f;
}
__device__ inline unsigned pkbf(float a, float b) {
    return ((unsigned)(unsigned short)f2bf(b) << 16) | (unsigned)(unsigned short)f2bf(a);
}
__device__ inline float ftanh(float x) {
    float e = __expf(2.f * x);
    return 1.f - 2.f / (e + 1.f);
}

__device__ inline f32x4 mfma16(short8 a, short8 b, f32x4 c) {
    return __builtin_amdgcn_mfma_f32_16x16x32_bf16(a, b, c, 0, 0, 0);
}

__device__ __forceinline__ void async_cp16(const short* g, short* l) {
    __builtin_amdgcn_global_load_lds(
        (const __attribute__((address_space(1))) void*)g,
        (__attribute__((address_space(3))) void*)l, 16, 0, 0);
}

// ---------------- LayerNorm (input) -> bf16 ; also zero-init lg ----------------
__global__ __launch_bounds__(128) void k_ln(const float* __restrict__ x,
                                            const float* __restrict__ g,
                                            const float* __restrict__ b,
                                            short* __restrict__ y,
                                            float* __restrict__ lg) {
    int tk = blockIdx.x, t = threadIdx.x;
    if (t == 0) lg[tk] = 0.f;
    float4 xv = ((const float4*)(x + (size_t)tk * DM))[t];
    float s = xv.x + xv.y + xv.z + xv.w;
    float q = xv.x*xv.x + xv.y*xv.y + xv.z*xv.z + xv.w*xv.w;
    for (int o = 32; o; o >>= 1) { s += __shfl_down(s, o); q += __shfl_down(q, o); }
    __shared__ float ls[2], lq[2];
    if ((t & 63) == 0) { ls[t >> 6] = s; lq[t >> 6] = q; }
    __syncthreads();
    s = ls[0] + ls[1]; q = lq[0] + lq[1];
    float mu = s * (1.f / DM);
    float var = q * (1.f / DM) - mu * mu;
    float rs = rsqrtf(var + 1e-5f);
    float4 gv = ((const float4*)g)[t], bv = ((const float4*)b)[t];
    short4_t o;
    o[0] = f2bf((xv.x - mu) * rs * gv.x + bv.x);
    o[1] = f2bf((xv.y - mu) * rs * gv.y + bv.y);
    o[2] = f2bf((xv.z - mu) * rs * gv.z + bv.z);
    o[3] = f2bf((xv.w - mu) * rs * gv.w + bv.w);
    *(short4_t*)&y[(size_t)tk * DM + t * 4] = o;
}

// ---------------- weight fp32 -> bf16 ----------------
__global__ __launch_bounds__(256) void k_cvtw(
    const float* __restrict__ Wq, const float* __restrict__ Wk,
    const float* __restrict__ Wv, const float* __restrict__ Tw1,
    const float* __restrict__ Wo,
    short* __restrict__ wcat, short* __restrict__ wo) {
    int id = blockIdx.x * 256 + threadIdx.x;
    if (id < 262144) {
        int z = id >> 16; int off = id & 65535;
        const float* s = (z == 0) ? Wq : (z == 1) ? Wk : (z == 2) ? Wv : Tw1;
        float4 v = ((const float4*)s)[off];
        short4_t o = {f2bf(v.x), f2bf(v.y), f2bf(v.z), f2bf(v.w)};
        *(short4_t*)(wcat + (size_t)z * 262144 + (size_t)off * 4) = o;
    } else {
        int off = id - 262144;
        float4 v = ((const float4*)Wo)[off];
        short4_t o = {f2bf(v.x), f2bf(v.y), f2bf(v.z), f2bf(v.w)};
        *(short4_t*)(wo + (size_t)off * 4) = o;
    }
}

// ---------------- bf16 MFMA NT-GEMM: C = A @ W^T ----------------
// qkvt=1: N=2048; z<3 scatters Q(x0.125)/K/V to [b][h][n][d] bf16;
//         z==3 computes partial T-logits: atomicAdd(lg, sum_col tanh(acc+b1)*w2)
// qkvt=0: N=512, writes proj fp32 [M][512]
__global__ __launch_bounds__(256) void k_gemm(
    const short* __restrict__ A, const short* __restrict__ W, int qkvt,
    const float* __restrict__ Tb1, const float* __restrict__ Tw2,
    short* __restrict__ qb, short* __restrict__ kb, short* __restrict__ vb,
    float* __restrict__ lg, float* __restrict__ proj) {
    __shared__ short As[128 * 32];
    __shared__ short Bs[128 * 32];
    int t = threadIdx.x;
    int lane = t & 63, w = t >> 6;
    int wy = w >> 1, wx = w & 1;
    int ln = lane & 15, q4 = lane >> 4;
    int c0 = blockIdx.x * 128, m0 = blockIdx.y * 128;
    int sr = t >> 2, sc = (t & 3) << 3;
    f32x4 acc[4][4];
    f32x4 zero = {0.f, 0.f, 0.f, 0.f};
    #pragma unroll
    for (int i = 0; i < 4; i++)
        #pragma unroll
        for (int j = 0; j < 4; j++) acc[i][j] = zero;
    for (int k0 = 0; k0 < DM; k0 += 32) {
        __syncthreads();
        async_cp16(&A[(size_t)(m0 + sr) * DM + k0 + sc],      &As[sr * 32 + sc]);
        async_cp16(&A[(size_t)(m0 + 64 + sr) * DM + k0 + sc], &As[(64 + sr) * 32 + sc]);
        async_cp16(&W[(size_t)(c0 + sr) * DM + k0 + sc],      &Bs[sr * 32 + sc]);
        async_cp16(&W[(size_t)(c0 + 64 + sr) * DM + k0 + sc], &Bs[(64 + sr) * 32 + sc]);
        __syncthreads();
        short8 af[4], bfr[4];
        #pragma unroll
        for (int i = 0; i < 4; i++)
            af[i] = *(short8*)&As[(wy * 64 + i * 16 + ln) * 32 + q4 * 8];
        #pragma unroll
        for (int j = 0; j < 4; j++)
            bfr[j] = *(short8*)&Bs[(wx * 64 + j * 16 + ln) * 32 + q4 * 8];
        #pragma unroll
        for (int i = 0; i < 4; i++)
            #pragma unroll
            for (int j = 0; j < 4; j++)
                acc[i][j] = mfma16(af[i], bfr[j], acc[i][j]);
    }
    if (qkvt) {
        int z = c0 >> 9;
        if (z < 3) {
            short* dst = (z == 0) ? qb : (z == 1) ? kb : vb;
            float sc2 = (z == 0) ? 0.125f : 1.0f;
            #pragma unroll
            for (int i = 0; i < 4; i++)
                #pragma unroll
                for (int j = 0; j < 4; j++)
                    #pragma unroll
                    for (int r = 0; r < 4; r++) {
                        int row = m0 + wy * 64 + i * 16 + q4 * 4 + r;
                        int col = c0 + wx * 64 + j * 16 + ln;
                        int nin = col & 511;
                        int h = nin >> 6, d = nin & 63;
                        int bi = row >> 11, n = row & (N_SEQ - 1);
                        dst[(((size_t)bi * NH + h) * N_SEQ + n) * HD + d] =
                            f2bf(acc[i][j][r] * sc2);
                    }
        } else {
            // T-logit partial: lg[row] += sum_col tanh(acc + b1[col]) * w2[col]
            #pragma unroll
            for (int i = 0; i < 4; i++) {
                #pragma unroll
                for (int r = 0; r < 4; r++) {
                    float s = 0.f;
                    #pragma unroll
                    for (int j = 0; j < 4; j++) {
                        int tc = (c0 & 511) + wx * 64 + j * 16 + ln;
                        s += ftanh(acc[i][j][r] + Tb1[tc]) * Tw2[tc];
                    }
                    s += __shfl_xor(s, 1);
                    s += __shfl_xor(s, 2);
                    s += __shfl_xor(s, 4);
                    s += __shfl_xor(s, 8);
                    if (ln == 0) {
                        int row = m0 + wy * 64 + i * 16 + q4 * 4 + r;
                        atomicAdd(&lg[row], s);
                    }
                }
            }
        }
    } else {
        #pragma unroll
        for (int i = 0; i < 4; i++)
            #pragma unroll
            for (int j = 0; j < 4; j++)
                #pragma unroll
                for (int r = 0; r < 4; r++) {
                    int row = m0 + wy * 64 + i * 16 + q4 * 4 + r;
                    int col = c0 + wx * 64 + j * 16 + ln;
                    proj[(size_t)row * DM + col] = acc[i][j][r];
                }
    }
}

// ---------------- V transpose: [b][h][n][d] -> [b][h][d][n] ----------------
__global__ __launch_bounds__(256) void k_vtr(const short* __restrict__ vb,
                                             short* __restrict__ vtb) {
    __shared__ short tile[64][80];
    int t = threadIdx.x;
    int n0 = blockIdx.x * 64, bh = blockIdx.y;
    const short* src = vb + (size_t)bh * N_SEQ * HD;
    short* dst = vtb + (size_t)bh * HD * N_SEQ;
    #pragma unroll
    for (int i = 0; i < 2; i++) {
        int id = t + 256 * i;
        int r = id >> 3, c = id & 7;
        *(short8*)&tile[r][c * 8] = *(const short8*)&src[(size_t)(n0 + r) * HD + c * 8];
    }
    __syncthreads();
    #pragma unroll
    for (int i = 0; i < 2; i++) {
        int id = t + 256 * i;
        int d = id >> 3, c = id & 7;
        short8 v;
        #pragma unroll
        for (int j = 0; j < 8; j++) v[j] = tile[c * 8 + j][d];
        *(short8*)&dst[(size_t)d * N_SEQ + n0 + c * 8] = v;
    }
}

// ---------------- gate softmax over sequence ----------------
__global__ __launch_bounds__(1024) void k_gate(const float* __restrict__ lg,
                                               float* __restrict__ gate) {
    int b = blockIdx.x, t = threadIdx.x;
    __shared__ float red[16];
    float v0 = lg[b * N_SEQ + t], v1 = lg[b * N_SEQ + 1024 + t];
    float m = fmaxf(v0, v1);
    for (int o = 32; o; o >>= 1) m = fmaxf(m, __shfl_down(m, o));
    if ((t & 63) == 0) red[t >> 6] = m;
    __syncthreads();
    if (t < 64) {
        float x = (t < 16) ? red[t] : -INFINITY;
        for (int o = 8; o; o >>= 1) x = fmaxf(x, __shfl_down(x, o));
        if (t == 0) red[0] = x;
    }
    __syncthreads();
    float M = red[0];
    float e0 = __expf(v0 - M), e1 = __expf(v1 - M);
    float s = e0 + e1;
    __syncthreads();
    for (int o = 32; o; o >>= 1) s += __shfl_down(s, o);
    if ((t & 63) == 0) red[t >> 6] = s;
    __syncthreads();
    if (t < 64) {
        float x = (t < 16) ? red[t] : 0.f;
        for (int o = 8; o; o >>= 1) x += __shfl_down(x, o);
        if (t == 0) red[0] = x;
    }
    __syncthreads();
    float inv = 1.f / red[0];
    gate[b * N_SEQ + t] = e0 * inv;
    gate[b * N_SEQ + 1024 + t] = e1 * inv;
}

// ---------------- split-K MFMA flash attention (S^T orientation) ----------------
// S^T = K·Q^T (rows=keys, cols=qrows) -> per-lane softmax state (1 qrow/lane)
// O^T = V^T·P^T via A=Vt rows (d), B=Pa rows (qrow). LDS rows padded to 72 shorts.
__global__ __launch_bounds__(256) void k_attn(const short* __restrict__ qb,
                                              const short* __restrict__ kb,
                                              const short* __restrict__ vtb,
                                              short* __restrict__ P_O,
                                              float* __restrict__ P_ml) {
    __shared__ short Ks[64 * 72];       // [key][d] pad72
    __shared__ short Vt[64 * 72];       // [d][key] pad72
    __shared__ short Pa[4][16 * 72];    // per-wave [qrow][key] pad72
    int t = threadIdx.x;
    int lane = t & 63, w = t >> 6;
    int ln = lane & 15, q4 = lane >> 4;
    int slot = blockIdx.x, qt = blockIdx.y, bi = blockIdx.z;
    int q0 = qt * 64;
    int h, c;
    if (slot < 7)        { h = 0; c = slot; }
    else if (slot < 14)  { h = 1; c = slot - 7; }
    else if (slot == 14) { h = 2; c = 0; }
    else if (slot == 15) { h = 3; c = 0; }
    else if (slot < 18)  { h = 4; c = slot - 16; }
    else if (slot == 18) { h = 5; c = 0; }
    else if (slot < 21)  { h = 6; c = slot - 19; }
    else                 { h = 7; c = slot - 21; }
    int kind = (h < 2) ? 0 : (h < 5) ? 1 : 2;
    int wnd = (h == 2 || h >= 5) ? 64 : (h == 3) ? 128 : (h == 4) ? 256 : 0;
    int dsh = (h == 5) ? 1 : (h == 6) ? 2 : (h == 7) ? 3 : 0;
    int dmask = (1 << dsh) - 1;
    int wmax = (kind == 0) ? 0 : (wnd << dsh);
    int tLoU, tHiU;
    if (kind == 0) { tLoU = 0; tHiU = 31; }
    else { tLoU = (q0 - wmax) >> 6; tHiU = (q0 + 63 + wmax) >> 6; }
    int ktLo = tLoU + c * CHUNK;
    int ktHi = ktLo + CHUNK - 1;
    if (ktHi > tHiU) ktHi = tHiU;
    if (ktHi > 31) ktHi = 31;
    if (ktLo < 0) ktLo = 0;
    int p4 = (bi * 32 + qt) * NSLOT + slot;
    float* ml = P_ml + (size_t)p4 * 128;
    if (ktLo > ktHi) {
        if (t < 64) { ml[t] = -1e30f; ml[64 + t] = 0.f; }
        return;
    }
    const size_t base = ((size_t)bi * NH + h) * N_SEQ * HD;
    const short* Q = qb + base;
    const short* K = kb + base;
    const short* Vg = vtb + base;   // [d][n]
    short8 qa[2];
    {
        const short* qrow = Q + (size_t)(q0 + w * 16 + ln) * HD + q4 * 8;
        qa[0] = *(const short8*)qrow;
        qa[1] = *(const short8*)(qrow + 32);
    }
    int qi = q0 + w * 16 + ln;      // this lane's q-row
    float m_i = -1e30f, l_i = 0.f;
    f32x4 OT[4];                     // OT[dt][reg]: d=dt*16+q4*4+reg, col=own qrow
    f32x4 zero = {0.f, 0.f, 0.f, 0.f};
    #pragma unroll
    for (int d = 0; d < 4; d++) OT[d] = zero;
    short* Paw = Pa[w];
    for (int kt = ktLo; kt <= ktHi; kt++) {
        int k0 = kt << 6;
        __syncthreads();
        #pragma unroll
        for (int i2 = 0; i2 < 2; i2++) {
            int id = t + 256 * i2;
            int r = id >> 3, cc = id & 7;
            *(short8*)&Ks[r * 72 + cc * 8] =
                *(const short8*)&K[(size_t)(k0 + r) * HD + cc * 8];
            *(short8*)&Vt[r * 72 + cc * 8] =
                *(const short8*)&Vg[(size_t)r * N_SEQ + k0 + cc * 8];
        }
        __syncthreads();
        // S^T = K·Q^T : ST[nt][reg] = S[key = k0+nt*16+q4*4+reg][qrow = qi]
        f32x4 ST[4];
        #pragma unroll
        for (int nt = 0; nt < 4; nt++) ST[nt] = zero;
        #pragma unroll
        for (int nt = 0; nt < 4; nt++) {
            #pragma unroll
            for (int ks = 0; ks < 2; ks++) {
                short8 af = *(short8*)&Ks[(nt * 16 + ln) * 72 + ks * 32 + q4 * 8];
                ST[nt] = mfma16(af, qa[ks], ST[nt]);
            }
        }
        // mask (in-lane) + online softmax (4 swizzles total)
        if (kind != 0) {
            #pragma unroll
            for (int nt = 0; nt < 4; nt++)
                #pragma unroll
                for (int r = 0; r < 4; r++) {
                    int key = k0 + nt * 16 + q4 * 4 + r;
                    int dlt = qi - key; dlt = (dlt < 0) ? -dlt : dlt;
                    int valid;
                    if (kind == 1) valid = (dlt <= wnd);
                    else valid = ((dlt & dmask) == 0) && ((dlt >> dsh) <= wnd);
                    if (!valid) ST[nt][r] = -1e30f;
                }
        }
        float rm = -1e30f;
        #pragma unroll
        for (int nt = 0; nt < 4; nt++) {
            float a = fmaxf(ST[nt][0], ST[nt][1]);
            float b = fmaxf(ST[nt][2], ST[nt][3]);
            rm = fmaxf(rm, fmaxf(a, b));
        }
        rm = fmaxf(rm, __shfl_xor(rm, 16));
        rm = fmaxf(rm, __shfl_xor(rm, 32));
        float mn = fmaxf(m_i, rm);
        float sc = __expf(m_i - mn);
        float rs = 0.f;
        #pragma unroll
        for (int nt = 0; nt < 4; nt++) {
            float p0 = __expf(ST[nt][0] - mn);
            float p1 = __expf(ST[nt][1] - mn);
            float p2 = __expf(ST[nt][2] - mn);
            float p3 = __expf(ST[nt][3] - mn);
            rs += (p0 + p1) + (p2 + p3);
            *(unsigned*)&Paw[ln * 72 + nt * 16 + q4 * 4]     = pkbf(p0, p1);
            *(unsigned*)&Paw[ln * 72 + nt * 16 + q4 * 4 + 2] = pkbf(p2, p3);
        }
        rs += __shfl_xor(rs, 16);
        rs += __shfl_xor(rs, 32);
        l_i = l_i * sc + rs;
        m_i = mn;
        #pragma unroll
        for (int d = 0; d < 4; d++) OT[d] *= sc;
        // O^T += V^T · P^T  (A = Vt rows d, B = Pa rows qrow; per-wave Pa)
        short8 pb0 = *(short8*)&Paw[ln * 72 + q4 * 8];
        short8 pb1 = *(short8*)&Paw[ln * 72 + 32 + q4 * 8];
        #pragma unroll
        for (int dt = 0; dt < 4; dt++) {
            short8 a0 = *(short8*)&Vt[(dt * 16 + ln) * 72 + q4 * 8];
            short8 a1 = *(short8*)&Vt[(dt * 16 + ln) * 72 + 32 + q4 * 8];
            OT[dt] = mfma16(a0, pb0, OT[dt]);
            OT[dt] = mfma16(a1, pb1, OT[dt]);
        }
    }
    // epilogue: ml + transpose O^T -> [row][d] via Paw, store bf16 partial
    if (q4 == 0) { ml[w * 16 + ln] = m_i; ml[64 + w * 16 + ln] = l_i; }
    #pragma unroll
    for (int dt = 0; dt < 4; dt++) {
        *(unsigned*)&Paw[ln * 72 + dt * 16 + q4 * 4]     = pkbf(OT[dt][0], OT[dt][1]);
        *(unsigned*)&Paw[ln * 72 + dt * 16 + q4 * 4 + 2] = pkbf(OT[dt][2], OT[dt][3]);
    }
    short8 o0 = *(short8*)&Paw[ln * 72 + q4 * 16];
    short8 o1 = *(short8*)&Paw[ln * 72 + q4 * 16 + 8];
    short* Op = P_O + (size_t)p4 * 4096;
    *(short8*)&Op[(w * 16 + ln) * 64 + q4 * 16] = o0;
    *(short8*)&Op[(w * 16 + ln) * 64 + q4 * 16 + 8] = o1;
}

// ---------------- combine partials -> obuf [b][n][512] bf16 ----------------
__global__ __launch_bounds__(256) void k_combine(const short* __restrict__ P_O,
                                                 const float* __restrict__ P_ml,
                                                 short* __restrict__ ob) {
    const int hbase[8] = {0, 7, 14, 15, 16, 18, 19, 21};
    const int hcnt[8]  = {7, 7, 1, 1, 2, 1, 2, 4};
    int h = blockIdx.x, qt = blockIdx.y, bi = blockIdx.z;
    int t = threadIdx.x;
    int row = t >> 2, c0 = (t & 3) * 16;
    int pb = (bi * 32 + qt) * NSLOT + hbase[h];
    int cnt = hcnt[h];
    float m = -1e30f;
    for (int s = 0; s < cnt; s++)
        m = fmaxf(m, P_ml[(size_t)(pb + s) * 128 + row]);
    float l = 0.f;
    float acc[16];
    #pragma unroll
    for (int j = 0; j < 16; j++) acc[j] = 0.f;
    for (int s = 0; s < cnt; s++) {
        float ms = P_ml[(size_t)(pb + s) * 128 + row];
        float ls = P_ml[(size_t)(pb + s) * 128 + 64 + row];
        if (ls > 0.f) {
            float sc = __expf(ms - m);
            l += ls * sc;
            const short* Op = P_O + (size_t)(pb + s) * 4096 + row * 64 + c0;
            short8 v0 = *(const short8*)Op;
            short8 v1 = *(const short8*)(Op + 8);
            #pragma unroll
            for (int j = 0; j < 8; j++) acc[j]     += bf2f(v0[j]) * sc;
            #pragma unroll
            for (int j = 0; j < 8; j++) acc[8 + j] += bf2f(v1[j]) * sc;
        }
    }
    float inv = 1.f / l;
    int n = qt * 64 + row;
    short8 o0, o1;
    #pragma unroll
    for (int j = 0; j < 8; j++) o0[j] = f2bf(acc[j] * inv);
    #pragma unroll
    for (int j = 0; j < 8; j++) o1[j] = f2bf(acc[8 + j] * inv);
    short* dst = ob + ((size_t)bi * N_SEQ + n) * DM + h * 64 + c0;
    *(short8*)dst = o0;
    *(short8*)(dst + 8) = o1;
}

// ---------------- final: y = proj*gate + x0 ; LN_out ----------------
__global__ __launch_bounds__(128) void k_final(const float* __restrict__ proj,
                                               const float* __restrict__ gate,
                                               const float* __restrict__ x0,
                                               const float* __restrict__ g,
                                               const float* __restrict__ b,
                                               float* __restrict__ out) {
    int tk = blockIdx.x, t = threadIdx.x;
    float gt = gate[tk];
    float4 pv = ((const float4*)(proj + (size_t)tk * DM))[t];
    float4 xv = ((const float4*)(x0 + (size_t)tk * DM))[t];
    float4 y;
    y.x = pv.x * gt + xv.x;
    y.y = pv.y * gt + xv.y;
    y.z = pv.z * gt + xv.z;
    y.w = pv.w * gt + xv.w;
    float s = y.x + y.y + y.z + y.w;
    float q = y.x*y.x + y.y*y.y + y.z*y.z + y.w*y.w;
    for (int o = 32; o; o >>= 1) { s += __shfl_down(s, o); q += __shfl_down(q, o); }
    __shared__ float ls[2], lq[2];
    if ((t & 63) == 0) { ls[t >> 6] = s; lq[t >> 6] = q; }
    __syncthreads();
    s = ls[0] + ls[1]; q = lq[0] + lq[1];
    float mu = s * (1.f / DM);
    float var = q * (1.f / DM) - mu * mu;
    float rs = rsqrtf(var + 1e-5f);
    float4 gv = ((const float4*)g)[t], bv = ((const float4*)b)[t];
    float4 o;
    o.x = (y.x - mu) * rs * gv.x + bv.x;
    o.y = (y.y - mu) * rs * gv.y + bv.y;
    o.z = (y.z - mu) * rs * gv.z + bv.z;
    o.w = (y.w - mu) * rs * gv.w + bv.w;
    ((float4*)(out + (size_t)tk * DM))[t] = o;
}

extern "C" void kernel_launch(void* const* d_in, const int* in_sizes, int n_in,
                              void* d_out, int out_size, void* d_ws, size_t ws_size,
                              hipStream_t stream) {
    (void)in_sizes; (void)n_in; (void)out_size; (void)ws_size;
    const float* x    = (const float*)d_in[0];
    const float* Wq   = (const float*)d_in[1];
    const float* Wk   = (const float*)d_in[2];
    const float* Wv   = (const float*)d_in[3];
    const float* Wo   = (const float*)d_in[4];
    const float* Tw1  = (const float*)d_in[5];
    const float* Tb1  = (const float*)d_in[6];
    const float* Tw2  = (const float*)d_in[7];
    const float* ling = (const float*)d_in[9];
    const float* linb = (const float*)d_in[10];
    const float* logg = (const float*)d_in[11];
    const float* logb = (const float*)d_in[12];
    float* out = (float*)d_out;

    const size_t SZ = (size_t)NTOK * DM;
    const int NPART = 2 * 32 * NSLOT;  // 1600 partial tiles
    char* p = (char*)d_ws;
    short* xn   = (short*)p; p += SZ * 2;
    short* wcat = (short*)p; p += (size_t)2048 * DM * 2;
    short* wo   = (short*)p; p += (size_t)DM * DM * 2;
    short* qb   = (short*)p; p += SZ * 2;
    short* kb   = (short*)p; p += SZ * 2;
    short* vb   = (short*)p; p += SZ * 2;
    short* vtb  = (short*)p; p += SZ * 2;
    short* obuf = (short*)p; p += SZ * 2;
    float* lg   = (float*)p; p += (size_t)NTOK * 4;
    float* gate = (float*)p; p += (size_t)NTOK * 4;
    float* P_ml = (float*)p; p += (size_t)NPART * 128 * 4;
    // proj (8 MB fp32) and P_O (12.8 MB bf16) share this region:
    // P_O is dead after k_combine; proj written only by the later Wo GEMM.
    float* proj = (float*)p;
    short* P_O  = (short*)p; p += (size_t)NPART * 4096 * 2;

    k_ln<<<NTOK, 128, 0, stream>>>(x, ling, linb, xn, lg);
    k_cvtw<<<1280, 256, 0, stream>>>(Wq, Wk, Wv, Tw1, Wo, wcat, wo);
    k_gemm<<<dim3(16, 32), 256, 0, stream>>>(xn, wcat, 1, Tb1, Tw2,
                                             qb, kb, vb, lg, nullptr);
    k_vtr<<<dim3(32, 16), 256, 0, stream>>>(vb, vtb);
    k_gate<<<2, 1024, 0, stream>>>(lg, gate);
    k_attn<<<dim3(NSLOT, 32, 2), 256, 0, stream>>>(qb, kb, vtb, P_O, P_ml);
    k_combine<<<dim3(8, 32, 2), 256, 0, stream>>>(P_O, P_ml, obuf);
    k_gemm<<<dim3(4, 32), 256, 0, stream>>>(obuf, wo, 0, nullptr, nullptr,
                                            nullptr, nullptr, nullptr, nullptr, proj);
    k_final<<<NTOK, 128, 0, stream>>>(proj, gate, x, logg, logb, out);
}

// Round 5
// 161.840 us; speedup vs baseline: 3.4509x; 1.0746x over previous
//
#include <hip/hip_runtime.h>
#include <math.h>

#define N_SEQ 2048
#define DM    512
#define NTOK  4096
#define NH    8
#define HD    64
#define NSLOT 18

typedef __attribute__((ext_vector_type(8))) short short8;
typedef __attribute__((ext_vector_type(4))) short short4_t;
typedef __attribute__((ext_vector_type(4))) float f32x4;

__device__ inline short f2bf(float x) {
    union { float f; unsigned u; } v; v.f = x;
    unsigned r = v.u + 0x7fff + ((v.u >> 16) & 1);
    return (short)(r >> 16);
}
__device__ inline float bf2f(short s) {
    union { unsigned u; float f; } v; v.u = ((unsigned)(unsigned short)s) << 16;
    return v.f;
}
__device__ inline unsigned pkbf(float a, float b) {
    return ((unsigned)(unsigned short)f2bf(b) << 16) | (unsigned)(unsigned short)f2bf(a);
}
__device__ inline float ftanh(float x) {
    float e = __expf(2.f * x);
    return 1.f - 2.f / (e + 1.f);
}

__device__ inline f32x4 mfma16(short8 a, short8 b, f32x4 c) {
    return __builtin_amdgcn_mfma_f32_16x16x32_bf16(a, b, c, 0, 0, 0);
}

__device__ __forceinline__ void async_cp16(const short* g, short* l) {
    __builtin_amdgcn_global_load_lds(
        (const __attribute__((address_space(1))) void*)g,
        (__attribute__((address_space(3))) void*)l, 16, 0, 0);
}

// ---------------- fused: LN(x)->bf16 + lg zero-init  |  weight cvt fp32->bf16 ----
// blocks 0..2047: 2 tokens each (256 thr). blocks 2048..3327: weight convert.
__global__ __launch_bounds__(256) void k_lncvt(
    const float* __restrict__ x, const float* __restrict__ g,
    const float* __restrict__ b, short* __restrict__ y, float* __restrict__ lg,
    const float* __restrict__ Wq, const float* __restrict__ Wk,
    const float* __restrict__ Wv, const float* __restrict__ Tw1,
    const float* __restrict__ Wo,
    short* __restrict__ wcat, short* __restrict__ wo) {
    int blk = blockIdx.x, t = threadIdx.x;
    if (blk < 2048) {
        int sub = t >> 7, tt = t & 127;
        int tk = blk * 2 + sub;
        if (tt == 0) lg[tk] = 0.f;
        float4 xv = ((const float4*)(x + (size_t)tk * DM))[tt];
        float s = xv.x + xv.y + xv.z + xv.w;
        float q = xv.x*xv.x + xv.y*xv.y + xv.z*xv.z + xv.w*xv.w;
        for (int o = 32; o; o >>= 1) { s += __shfl_down(s, o); q += __shfl_down(q, o); }
        __shared__ float ls[4], lq[4];
        if ((t & 63) == 0) { ls[t >> 6] = s; lq[t >> 6] = q; }
        __syncthreads();
        s = ls[sub * 2] + ls[sub * 2 + 1];
        q = lq[sub * 2] + lq[sub * 2 + 1];
        float mu = s * (1.f / DM);
        float var = q * (1.f / DM) - mu * mu;
        float rs = rsqrtf(var + 1e-5f);
        float4 gv = ((const float4*)g)[tt], bv = ((const float4*)b)[tt];
        short4_t o;
        o[0] = f2bf((xv.x - mu) * rs * gv.x + bv.x);
        o[1] = f2bf((xv.y - mu) * rs * gv.y + bv.y);
        o[2] = f2bf((xv.z - mu) * rs * gv.z + bv.z);
        o[3] = f2bf((xv.w - mu) * rs * gv.w + bv.w);
        *(short4_t*)&y[(size_t)tk * DM + tt * 4] = o;
    } else {
        int id = (blk - 2048) * 256 + t;
        if (id < 262144) {
            int z = id >> 16; int off = id & 65535;
            const float* s = (z == 0) ? Wq : (z == 1) ? Wk : (z == 2) ? Wv : Tw1;
            float4 v = ((const float4*)s)[off];
            short4_t o = {f2bf(v.x), f2bf(v.y), f2bf(v.z), f2bf(v.w)};
            *(short4_t*)(wcat + (size_t)z * 262144 + (size_t)off * 4) = o;
        } else {
            int off = id - 262144;
            float4 v = ((const float4*)Wo)[off];
            short4_t o = {f2bf(v.x), f2bf(v.y), f2bf(v.z), f2bf(v.w)};
            *(short4_t*)(wo + (size_t)off * 4) = o;
        }
    }
}

// ---------------- bf16 MFMA NT-GEMM (QKV + T-logit fused) ----------------
__global__ __launch_bounds__(256) void k_gemmqkvt(
    const short* __restrict__ A, const short* __restrict__ W,
    const float* __restrict__ Tb1, const float* __restrict__ Tw2,
    short* __restrict__ qb, short* __restrict__ kb, short* __restrict__ vb,
    float* __restrict__ lg) {
    __shared__ short As[128 * 32];
    __shared__ short Bs[128 * 32];
    int t = threadIdx.x;
    int lane = t & 63, w = t >> 6;
    int wy = w >> 1, wx = w & 1;
    int ln = lane & 15, q4 = lane >> 4;
    int c0 = blockIdx.x * 128, m0 = blockIdx.y * 128;
    int sr = t >> 2, sc = (t & 3) << 3;
    f32x4 acc[4][4];
    f32x4 zero = {0.f, 0.f, 0.f, 0.f};
    #pragma unroll
    for (int i = 0; i < 4; i++)
        #pragma unroll
        for (int j = 0; j < 4; j++) acc[i][j] = zero;
    for (int k0 = 0; k0 < DM; k0 += 32) {
        __syncthreads();
        async_cp16(&A[(size_t)(m0 + sr) * DM + k0 + sc],      &As[sr * 32 + sc]);
        async_cp16(&A[(size_t)(m0 + 64 + sr) * DM + k0 + sc], &As[(64 + sr) * 32 + sc]);
        async_cp16(&W[(size_t)(c0 + sr) * DM + k0 + sc],      &Bs[sr * 32 + sc]);
        async_cp16(&W[(size_t)(c0 + 64 + sr) * DM + k0 + sc], &Bs[(64 + sr) * 32 + sc]);
        __syncthreads();
        short8 af[4], bfr[4];
        #pragma unroll
        for (int i = 0; i < 4; i++)
            af[i] = *(short8*)&As[(wy * 64 + i * 16 + ln) * 32 + q4 * 8];
        #pragma unroll
        for (int j = 0; j < 4; j++)
            bfr[j] = *(short8*)&Bs[(wx * 64 + j * 16 + ln) * 32 + q4 * 8];
        #pragma unroll
        for (int i = 0; i < 4; i++)
            #pragma unroll
            for (int j = 0; j < 4; j++)
                acc[i][j] = mfma16(af[i], bfr[j], acc[i][j]);
    }
    int z = c0 >> 9;
    if (z < 3) {
        short* dst = (z == 0) ? qb : (z == 1) ? kb : vb;
        float sc2 = (z == 0) ? 0.125f : 1.0f;
        #pragma unroll
        for (int i = 0; i < 4; i++)
            #pragma unroll
            for (int j = 0; j < 4; j++)
                #pragma unroll
                for (int r = 0; r < 4; r++) {
                    int row = m0 + wy * 64 + i * 16 + q4 * 4 + r;
                    int col = c0 + wx * 64 + j * 16 + ln;
                    int nin = col & 511;
                    int h = nin >> 6, d = nin & 63;
                    int bi = row >> 11, n = row & (N_SEQ - 1);
                    dst[(((size_t)bi * NH + h) * N_SEQ + n) * HD + d] =
                        f2bf(acc[i][j][r] * sc2);
                }
    } else {
        #pragma unroll
        for (int i = 0; i < 4; i++) {
            #pragma unroll
            for (int r = 0; r < 4; r++) {
                float s = 0.f;
                #pragma unroll
                for (int j = 0; j < 4; j++) {
                    int tc = (c0 & 511) + wx * 64 + j * 16 + ln;
                    s += ftanh(acc[i][j][r] + Tb1[tc]) * Tw2[tc];
                }
                s += __shfl_xor(s, 1);
                s += __shfl_xor(s, 2);
                s += __shfl_xor(s, 4);
                s += __shfl_xor(s, 8);
                if (ln == 0) {
                    int row = m0 + wy * 64 + i * 16 + q4 * 4 + r;
                    atomicAdd(&lg[row], s);
                }
            }
        }
    }
}

// ---------------- proj GEMM 128x64 tiles: proj = A @ Wo^T ----------------
__global__ __launch_bounds__(256) void k_gemmp(
    const short* __restrict__ A, const short* __restrict__ W,
    float* __restrict__ proj) {
    __shared__ short As[128 * 32];
    __shared__ short Bs[64 * 32];
    int t = threadIdx.x;
    int lane = t & 63, w = t >> 6;
    int wy = w >> 1, wx = w & 1;
    int ln = lane & 15, q4 = lane >> 4;
    int c0 = blockIdx.x * 64, m0 = blockIdx.y * 128;
    int sr = t >> 2, sc = (t & 3) << 3;
    int br = t >> 2, bc = (t & 3) << 3;  // 64 rows need only t<256/4*... (t>>2 in 0..63)
    f32x4 acc[4][2];
    f32x4 zero = {0.f, 0.f, 0.f, 0.f};
    #pragma unroll
    for (int i = 0; i < 4; i++) { acc[i][0] = zero; acc[i][1] = zero; }
    for (int k0 = 0; k0 < DM; k0 += 32) {
        __syncthreads();
        async_cp16(&A[(size_t)(m0 + sr) * DM + k0 + sc],      &As[sr * 32 + sc]);
        async_cp16(&A[(size_t)(m0 + 64 + sr) * DM + k0 + sc], &As[(64 + sr) * 32 + sc]);
        if (br < 64)
            async_cp16(&W[(size_t)(c0 + br) * DM + k0 + bc], &Bs[br * 32 + bc]);
        __syncthreads();
        short8 af[4], bfr[2];
        #pragma unroll
        for (int i = 0; i < 4; i++)
            af[i] = *(short8*)&As[(wy * 64 + i * 16 + ln) * 32 + q4 * 8];
        #pragma unroll
        for (int j = 0; j < 2; j++)
            bfr[j] = *(short8*)&Bs[(wx * 32 + j * 16 + ln) * 32 + q4 * 8];
        #pragma unroll
        for (int i = 0; i < 4; i++)
            #pragma unroll
            for (int j = 0; j < 2; j++)
                acc[i][j] = mfma16(af[i], bfr[j], acc[i][j]);
    }
    #pragma unroll
    for (int i = 0; i < 4; i++)
        #pragma unroll
        for (int j = 0; j < 2; j++)
            #pragma unroll
            for (int r = 0; r < 4; r++) {
                int row = m0 + wy * 64 + i * 16 + q4 * 4 + r;
                int col = c0 + wx * 32 + j * 16 + ln;
                proj[(size_t)row * DM + col] = acc[i][j][r];
            }
}

// ---------------- fused: V transpose | gate softmax ----------------
// blocks 0..511: vtr. blocks 512,513: gate softmax for batch b=blk-512.
__global__ __launch_bounds__(256) void k_vtrgate(const short* __restrict__ vb,
                                                 short* __restrict__ vtb,
                                                 const float* __restrict__ lg,
                                                 float* __restrict__ gate) {
    __shared__ short tile[64][80];
    __shared__ float rg[8];
    int blk = blockIdx.x, t = threadIdx.x;
    if (blk < 512) {
        int n0 = (blk & 31) * 64, bh = blk >> 5;
        const short* src = vb + (size_t)bh * N_SEQ * HD;
        short* dst = vtb + (size_t)bh * HD * N_SEQ;
        #pragma unroll
        for (int i = 0; i < 2; i++) {
            int id = t + 256 * i;
            int r = id >> 3, c = id & 7;
            *(short8*)&tile[r][c * 8] = *(const short8*)&src[(size_t)(n0 + r) * HD + c * 8];
        }
        __syncthreads();
        #pragma unroll
        for (int i = 0; i < 2; i++) {
            int id = t + 256 * i;
            int d = id >> 3, c = id & 7;
            short8 v;
            #pragma unroll
            for (int j = 0; j < 8; j++) v[j] = tile[c * 8 + j][d];
            *(short8*)&dst[(size_t)d * N_SEQ + n0 + c * 8] = v;
        }
    } else {
        int b = blk - 512;
        float v[8];
        {
            float4 a0 = *(const float4*)&lg[b * N_SEQ + t * 8];
            float4 a1 = *(const float4*)&lg[b * N_SEQ + t * 8 + 4];
            v[0] = a0.x; v[1] = a0.y; v[2] = a0.z; v[3] = a0.w;
            v[4] = a1.x; v[5] = a1.y; v[6] = a1.z; v[7] = a1.w;
        }
        float m = v[0];
        #pragma unroll
        for (int j = 1; j < 8; j++) m = fmaxf(m, v[j]);
        for (int o = 32; o; o >>= 1) m = fmaxf(m, __shfl_down(m, o));
        if ((t & 63) == 0) rg[t >> 6] = m;
        __syncthreads();
        m = fmaxf(fmaxf(rg[0], rg[1]), fmaxf(rg[2], rg[3]));
        float e[8], s = 0.f;
        #pragma unroll
        for (int j = 0; j < 8; j++) { e[j] = __expf(v[j] - m); s += e[j]; }
        for (int o = 32; o; o >>= 1) s += __shfl_down(s, o);
        if ((t & 63) == 0) rg[4 + (t >> 6)] = s;
        __syncthreads();
        s = (rg[4] + rg[5]) + (rg[6] + rg[7]);
        float inv = 1.f / s;
        float4 o0 = {e[0] * inv, e[1] * inv, e[2] * inv, e[3] * inv};
        float4 o1 = {e[4] * inv, e[5] * inv, e[6] * inv, e[7] * inv};
        *(float4*)&gate[b * N_SEQ + t * 8] = o0;
        *(float4*)&gate[b * N_SEQ + t * 8 + 4] = o1;
    }
}

// ---------------- split-K MFMA flash attention, 128-key tiles ----------------
// 18 slots: h0:0-3 h1:4-7 h2:8 h3:9 h4:10-11 h5:12 h6:13-14 h7:15-17
__global__ __launch_bounds__(256) void k_attn(const short* __restrict__ qb,
                                              const short* __restrict__ kb,
                                              const short* __restrict__ vtb,
                                              short* __restrict__ P_O,
                                              float* __restrict__ P_ml) {
    __shared__ short Ks[128 * 72];      // [key][d] pad72
    __shared__ short Vt[64 * 136];      // [d][key] pad136
    __shared__ short Pa[4][16 * 136];   // per-wave [qrow][key] pad136
    int t = threadIdx.x;
    int lane = t & 63, w = t >> 6;
    int ln = lane & 15, q4 = lane >> 4;
    int slot = blockIdx.x, qt = blockIdx.y, bi = blockIdx.z;
    int q0 = qt * 64;
    int h, c;
    if (slot < 4)        { h = 0; c = slot; }
    else if (slot < 8)   { h = 1; c = slot - 4; }
    else if (slot == 8)  { h = 2; c = 0; }
    else if (slot == 9)  { h = 3; c = 0; }
    else if (slot < 12)  { h = 4; c = slot - 10; }
    else if (slot == 12) { h = 5; c = 0; }
    else if (slot < 15)  { h = 6; c = slot - 13; }
    else                 { h = 7; c = slot - 15; }
    int kind = (h < 2) ? 0 : (h < 5) ? 1 : 2;
    int wnd = (h == 2 || h >= 5) ? 64 : (h == 3) ? 128 : (h == 4) ? 256 : 0;
    int dsh = (h == 5) ? 1 : (h == 6) ? 2 : (h == 7) ? 3 : 0;
    int dmask = (1 << dsh) - 1;
    int wmax = (kind == 0) ? 0 : (wnd << dsh);
    int tLoU, tHiU, CS;
    if (kind == 0) { tLoU = 0; tHiU = 15; CS = 4; }
    else { tLoU = (q0 - wmax) >> 7; tHiU = (q0 + 63 + wmax) >> 7; CS = 3; }
    int ktLo = tLoU + c * CS;
    int ktHi = ktLo + CS - 1;
    if (ktHi > tHiU) ktHi = tHiU;
    if (ktHi > 15) ktHi = 15;
    if (ktLo < 0) ktLo = 0;
    int p4 = (bi * 32 + qt) * NSLOT + slot;
    float* ml = P_ml + (size_t)p4 * 128;
    if (ktLo > ktHi) {
        if (t < 64) { ml[t] = -1e30f; ml[64 + t] = 0.f; }
        return;
    }
    const size_t base = ((size_t)bi * NH + h) * N_SEQ * HD;
    const short* Q = qb + base;
    const short* K = kb + base;
    const short* Vg = vtb + base;   // [d][n]
    short8 qa[2];
    {
        const short* qrow = Q + (size_t)(q0 + w * 16 + ln) * HD + q4 * 8;
        qa[0] = *(const short8*)qrow;
        qa[1] = *(const short8*)(qrow + 32);
    }
    int qi = q0 + w * 16 + ln;
    float m_i = -1e30f, l_i = 0.f;
    f32x4 OT[4];
    f32x4 zero = {0.f, 0.f, 0.f, 0.f};
    #pragma unroll
    for (int d = 0; d < 4; d++) OT[d] = zero;
    short* Paw = Pa[w];
    for (int kt = ktLo; kt <= ktHi; kt++) {
        int k0 = kt << 7;
        __syncthreads();
        #pragma unroll
        for (int i2 = 0; i2 < 4; i2++) {
            int id = t + 256 * i2;
            int kr = id >> 3, cc = id & 7;
            *(short8*)&Ks[kr * 72 + cc * 8] =
                *(const short8*)&K[(size_t)(k0 + kr) * HD + cc * 8];
            int dr = id >> 4, kc = id & 15;
            *(short8*)&Vt[dr * 136 + kc * 8] =
                *(const short8*)&Vg[(size_t)dr * N_SEQ + k0 + kc * 8];
        }
        __syncthreads();
        // S^T = K·Q^T over 128 keys
        f32x4 ST[8];
        #pragma unroll
        for (int nt = 0; nt < 8; nt++) ST[nt] = zero;
        #pragma unroll
        for (int nt = 0; nt < 8; nt++) {
            #pragma unroll
            for (int ks = 0; ks < 2; ks++) {
                short8 af = *(short8*)&Ks[(nt * 16 + ln) * 72 + ks * 32 + q4 * 8];
                ST[nt] = mfma16(af, qa[ks], ST[nt]);
            }
        }
        if (kind != 0) {
            #pragma unroll
            for (int nt = 0; nt < 8; nt++)
                #pragma unroll
                for (int r = 0; r < 4; r++) {
                    int key = k0 + nt * 16 + q4 * 4 + r;
                    int dlt = qi - key; dlt = (dlt < 0) ? -dlt : dlt;
                    int valid;
                    if (kind == 1) valid = (dlt <= wnd);
                    else valid = ((dlt & dmask) == 0) && ((dlt >> dsh) <= wnd);
                    if (!valid) ST[nt][r] = -1e30f;
                }
        }
        float rm = -1e30f;
        #pragma unroll
        for (int nt = 0; nt < 8; nt++) {
            float a = fmaxf(ST[nt][0], ST[nt][1]);
            float b = fmaxf(ST[nt][2], ST[nt][3]);
            rm = fmaxf(rm, fmaxf(a, b));
        }
        rm = fmaxf(rm, __shfl_xor(rm, 16));
        rm = fmaxf(rm, __shfl_xor(rm, 32));
        float mn = fmaxf(m_i, rm);
        float sc = __expf(m_i - mn);
        float rs = 0.f;
        #pragma unroll
        for (int nt = 0; nt < 8; nt++) {
            float p0 = __expf(ST[nt][0] - mn);
            float p1 = __expf(ST[nt][1] - mn);
            float p2 = __expf(ST[nt][2] - mn);
            float p3 = __expf(ST[nt][3] - mn);
            rs += (p0 + p1) + (p2 + p3);
            *(unsigned*)&Paw[ln * 136 + nt * 16 + q4 * 4]     = pkbf(p0, p1);
            *(unsigned*)&Paw[ln * 136 + nt * 16 + q4 * 4 + 2] = pkbf(p2, p3);
        }
        rs += __shfl_xor(rs, 16);
        rs += __shfl_xor(rs, 32);
        l_i = l_i * sc + rs;
        m_i = mn;
        #pragma unroll
        for (int d = 0; d < 4; d++) OT[d] *= sc;
        // O^T += V^T · P^T
        short8 pb[4];
        #pragma unroll
        for (int ks = 0; ks < 4; ks++)
            pb[ks] = *(short8*)&Paw[ln * 136 + ks * 32 + q4 * 8];
        #pragma unroll
        for (int dt = 0; dt < 4; dt++) {
            #pragma unroll
            for (int ks = 0; ks < 4; ks++) {
                short8 a = *(short8*)&Vt[(dt * 16 + ln) * 136 + ks * 32 + q4 * 8];
                OT[dt] = mfma16(a, pb[ks], OT[dt]);
            }
        }
    }
    if (q4 == 0) { ml[w * 16 + ln] = m_i; ml[64 + w * 16 + ln] = l_i; }
    #pragma unroll
    for (int dt = 0; dt < 4; dt++) {
        *(unsigned*)&Paw[ln * 136 + dt * 16 + q4 * 4]     = pkbf(OT[dt][0], OT[dt][1]);
        *(unsigned*)&Paw[ln * 136 + dt * 16 + q4 * 4 + 2] = pkbf(OT[dt][2], OT[dt][3]);
    }
    short8 o0 = *(short8*)&Paw[ln * 136 + q4 * 16];
    short8 o1 = *(short8*)&Paw[ln * 136 + q4 * 16 + 8];
    short* Op = P_O + (size_t)p4 * 4096;
    *(short8*)&Op[(w * 16 + ln) * 64 + q4 * 16] = o0;
    *(short8*)&Op[(w * 16 + ln) * 64 + q4 * 16 + 8] = o1;
}

// ---------------- combine partials -> obuf [b][n][512] bf16 ----------------
__global__ __launch_bounds__(256) void k_combine(const short* __restrict__ P_O,
                                                 const float* __restrict__ P_ml,
                                                 short* __restrict__ ob) {
    const int hbase[8] = {0, 4, 8, 9, 10, 12, 13, 15};
    const int hcnt[8]  = {4, 4, 1, 1, 2, 1, 2, 3};
    int h = blockIdx.x, qt = blockIdx.y, bi = blockIdx.z;
    int t = threadIdx.x;
    int row = t >> 2, c0 = (t & 3) * 16;
    int pb = (bi * 32 + qt) * NSLOT + hbase[h];
    int cnt = hcnt[h];
    float m = -1e30f;
    for (int s = 0; s < cnt; s++)
        m = fmaxf(m, P_ml[(size_t)(pb + s) * 128 + row]);
    float l = 0.f;
    float acc[16];
    #pragma unroll
    for (int j = 0; j < 16; j++) acc[j] = 0.f;
    for (int s = 0; s < cnt; s++) {
        float ms = P_ml[(size_t)(pb + s) * 128 + row];
        float ls = P_ml[(size_t)(pb + s) * 128 + 64 + row];
        if (ls > 0.f) {
            float sc = __expf(ms - m);
            l += ls * sc;
            const short* Op = P_O + (size_t)(pb + s) * 4096 + row * 64 + c0;
            short8 v0 = *(const short8*)Op;
            short8 v1 = *(const short8*)(Op + 8);
            #pragma unroll
            for (int j = 0; j < 8; j++) acc[j]     += bf2f(v0[j]) * sc;
            #pragma unroll
            for (int j = 0; j < 8; j++) acc[8 + j] += bf2f(v1[j]) * sc;
        }
    }
    float inv = 1.f / l;
    int n = qt * 64 + row;
    short8 o0, o1;
    #pragma unroll
    for (int j = 0; j < 8; j++) o0[j] = f2bf(acc[j] * inv);
    #pragma unroll
    for (int j = 0; j < 8; j++) o1[j] = f2bf(acc[8 + j] * inv);
    short* dst = ob + ((size_t)bi * N_SEQ + n) * DM + h * 64 + c0;
    *(short8*)dst = o0;
    *(short8*)(dst + 8) = o1;
}

// ---------------- final: y = proj*gate + x0 ; LN_out ----------------
__global__ __launch_bounds__(128) void k_final(const float* __restrict__ proj,
                                               const float* __restrict__ gate,
                                               const float* __restrict__ x0,
                                               const float* __restrict__ g,
                                               const float* __restrict__ b,
                                               float* __restrict__ out) {
    int tk = blockIdx.x, t = threadIdx.x;
    float gt = gate[tk];
    float4 pv = ((const float4*)(proj + (size_t)tk * DM))[t];
    float4 xv = ((const float4*)(x0 + (size_t)tk * DM))[t];
    float4 y;
    y.x = pv.x * gt + xv.x;
    y.y = pv.y * gt + xv.y;
    y.z = pv.z * gt + xv.z;
    y.w = pv.w * gt + xv.w;
    float s = y.x + y.y + y.z + y.w;
    float q = y.x*y.x + y.y*y.y + y.z*y.z + y.w*y.w;
    for (int o = 32; o; o >>= 1) { s += __shfl_down(s, o); q += __shfl_down(q, o); }
    __shared__ float ls[2], lq[2];
    if ((t & 63) == 0) { ls[t >> 6] = s; lq[t >> 6] = q; }
    __syncthreads();
    s = ls[0] + ls[1]; q = lq[0] + lq[1];
    float mu = s * (1.f / DM);
    float var = q * (1.f / DM) - mu * mu;
    float rs = rsqrtf(var + 1e-5f);
    float4 gv = ((const float4*)g)[t], bv = ((const float4*)b)[t];
    float4 o;
    o.x = (y.x - mu) * rs * gv.x + bv.x;
    o.y = (y.y - mu) * rs * gv.y + bv.y;
    o.z = (y.z - mu) * rs * gv.z + bv.z;
    o.w = (y.w - mu) * rs * gv.w + bv.w;
    ((float4*)(out + (size_t)tk * DM))[t] = o;
}

extern "C" void kernel_launch(void* const* d_in, const int* in_sizes, int n_in,
                              void* d_out, int out_size, void* d_ws, size_t ws_size,
                              hipStream_t stream) {
    (void)in_sizes; (void)n_in; (void)out_size; (void)ws_size;
    const float* x    = (const float*)d_in[0];
    const float* Wq   = (const float*)d_in[1];
    const float* Wk   = (const float*)d_in[2];
    const float* Wv   = (const float*)d_in[3];
    const float* Wo   = (const float*)d_in[4];
    const float* Tw1  = (const float*)d_in[5];
    const float* Tb1  = (const float*)d_in[6];
    const float* Tw2  = (const float*)d_in[7];
    const float* ling = (const float*)d_in[9];
    const float* linb = (const float*)d_in[10];
    const float* logg = (const float*)d_in[11];
    const float* logb = (const float*)d_in[12];
    float* out = (float*)d_out;

    const size_t SZ = (size_t)NTOK * DM;
    const int NPART = 2 * 32 * NSLOT;  // 1152 partial tiles
    char* p = (char*)d_ws;
    short* xn   = (short*)p; p += SZ * 2;
    short* wcat = (short*)p; p += (size_t)2048 * DM * 2;
    short* wo   = (short*)p; p += (size_t)DM * DM * 2;
    short* qb   = (short*)p; p += SZ * 2;
    short* kb   = (short*)p; p += SZ * 2;
    short* vb   = (short*)p; p += SZ * 2;
    short* vtb  = (short*)p; p += SZ * 2;
    short* obuf = (short*)p; p += SZ * 2;
    float* lg   = (float*)p; p += (size_t)NTOK * 4;
    float* gate = (float*)p; p += (size_t)NTOK * 4;
    float* P_ml = (float*)p; p += (size_t)NPART * 128 * 4;
    // proj (8 MB fp32) aliases P_O (9.4 MB bf16): P_O dead after k_combine;
    // proj written only by the later Wo GEMM.
    float* proj = (float*)p;
    short* P_O  = (short*)p; p += (size_t)NPART * 4096 * 2;

    k_lncvt<<<3328, 256, 0, stream>>>(x, ling, linb, xn, lg,
                                      Wq, Wk, Wv, Tw1, Wo, wcat, wo);
    k_gemmqkvt<<<dim3(16, 32), 256, 0, stream>>>(xn, wcat, Tb1, Tw2,
                                                 qb, kb, vb, lg);
    k_vtrgate<<<514, 256, 0, stream>>>(vb, vtb, lg, gate);
    k_attn<<<dim3(NSLOT, 32, 2), 256, 0, stream>>>(qb, kb, vtb, P_O, P_ml);
    k_combine<<<dim3(8, 32, 2), 256, 0, stream>>>(P_O, P_ml, obuf);
    k_gemmp<<<dim3(8, 32), 256, 0, stream>>>(obuf, wo, proj);
    k_final<<<NTOK, 128, 0, stream>>>(proj, gate, x, logg, logb, out);
}